// Round 4
// baseline (6691.431 us; speedup 1.0000x reference)
//
#include <hip/hip_runtime.h>
#include <math.h>

#define B_    4
#define T_ENC 512
#define ML_   1024
#define D_    512
#define H_    8
#define HD_   64
#define FF_   2048
#define FS_   256
#define NMEL_ 80
#define PN_   512
#define L_    4
#define QKVSTRIDE_ 2097152

// ---------------------------------------------------------------- embed
__global__ void embed_kernel(const int* __restrict__ text, const float* __restrict__ emb,
                             const float* __restrict__ pos, float* __restrict__ x) {
    int row = blockIdx.x;            // b*T + t
    int t = row % T_ENC;
    int tok = text[row];
    float4 e = ((const float4*)(emb + (size_t)tok * D_))[threadIdx.x];
    float4 p = ((const float4*)(pos + (size_t)t * D_))[threadIdx.x];
    e.x += p.x; e.y += p.y; e.z += p.z; e.w += p.w;
    ((float4*)(x + (size_t)row * D_))[threadIdx.x] = e;
}

// ---------------------------------------------------------------- layernorm (row per block)
__global__ __launch_bounds__(256)
void ln_kernel(const float* __restrict__ x, const float* __restrict__ g,
               const float* __restrict__ b, float* __restrict__ out, int D) {
    __shared__ float ls[256], lq[256];
    int row = blockIdx.x, tid = threadIdx.x;
    const float* xr = x + (size_t)row * D;
    float s = 0.f, q = 0.f;
    for (int d = tid; d < D; d += 256) { float v = xr[d]; s += v; q += v * v; }
    ls[tid] = s; lq[tid] = q; __syncthreads();
    for (int off = 128; off; off >>= 1) {
        if (tid < off) { ls[tid] += ls[tid + off]; lq[tid] += lq[tid + off]; }
        __syncthreads();
    }
    float mean = ls[0] / D;
    float var  = lq[0] / D - mean * mean;
    float rstd = rsqrtf(var + 1e-5f);
    float* orow = out + (size_t)row * D;
    for (int d = tid; d < D; d += 256) orow[d] = (xr[d] - mean) * rstd * g[d] + b[d];
}

// ---------------------------------------------------------------- small GEMM (kept for mel proj)
enum { EPI_STORE = 0, EPI_ADD = 1, EPI_GELU = 2, EPI_QKV = 3, EPI_BIAS = 4 };

template<int EPI, bool QUANT>
__global__ __launch_bounds__(256)
void gemm_kernel(const float* __restrict__ X, const void* __restrict__ Wv,
                 const float* __restrict__ lut, const float* __restrict__ scale,
                 const float* __restrict__ bias, float* __restrict__ out,
                 int N, int M, int K, int Ttok, int ldo) {
    __shared__ float Xs[16][68];
    __shared__ float Ws[16][68];
    int tid = threadIdx.x;
    int n0 = blockIdx.x * 64, m0 = blockIdx.y * 64;
    int tx = tid & 15, ty = tid >> 4;
    int nl = tid >> 2, kq = (tid & 3) * 4;
    const float* Xp = X + (size_t)(n0 + nl) * K + kq;
    const float* Wf = (const float*)Wv;
    size_t wrow = (size_t)(m0 + nl) * K + kq;
    bool wok = (m0 + nl) < M;
    float c[4][4] = {{0.f}};
    for (int k0 = 0; k0 < K; k0 += 16) {
        __syncthreads();
        float4 xv = *(const float4*)(Xp + k0);
        float w0, w1, w2, w3;
        if (wok) {
            float4 w4 = *(const float4*)(Wf + wrow + k0);
            w0 = w4.x; w1 = w4.y; w2 = w4.z; w3 = w4.w;
        } else { w0 = w1 = w2 = w3 = 0.f; }
        Xs[kq + 0][nl] = xv.x; Xs[kq + 1][nl] = xv.y; Xs[kq + 2][nl] = xv.z; Xs[kq + 3][nl] = xv.w;
        Ws[kq + 0][nl] = w0;   Ws[kq + 1][nl] = w1;   Ws[kq + 2][nl] = w2;   Ws[kq + 3][nl] = w3;
        __syncthreads();
#pragma unroll
        for (int kk = 0; kk < 16; kk++) {
            float4 a = *(const float4*)&Xs[kk][ty * 4];
            float4 w = *(const float4*)&Ws[kk][tx * 4];
            c[0][0] = fmaf(a.x, w.x, c[0][0]); c[0][1] = fmaf(a.x, w.y, c[0][1]);
            c[0][2] = fmaf(a.x, w.z, c[0][2]); c[0][3] = fmaf(a.x, w.w, c[0][3]);
            c[1][0] = fmaf(a.y, w.x, c[1][0]); c[1][1] = fmaf(a.y, w.y, c[1][1]);
            c[1][2] = fmaf(a.y, w.z, c[1][2]); c[1][3] = fmaf(a.y, w.w, c[1][3]);
            c[2][0] = fmaf(a.z, w.x, c[2][0]); c[2][1] = fmaf(a.z, w.y, c[2][1]);
            c[2][2] = fmaf(a.z, w.z, c[2][2]); c[2][3] = fmaf(a.z, w.w, c[2][3]);
            c[3][0] = fmaf(a.w, w.x, c[3][0]); c[3][1] = fmaf(a.w, w.y, c[3][1]);
            c[3][2] = fmaf(a.w, w.z, c[3][2]); c[3][3] = fmaf(a.w, w.w, c[3][3]);
        }
    }
#pragma unroll
    for (int i = 0; i < 4; i++) {
        int n = n0 + ty * 4 + i;
#pragma unroll
        for (int j = 0; j < 4; j++) {
            int m = m0 + tx * 4 + j;
            float v = c[i][j];
            if (EPI == EPI_BIAS) {
                if (m < M) out[(size_t)n * ldo + m] = v + bias[m];
            } else if (EPI == EPI_STORE) {
                if (m < M) out[(size_t)n * ldo + m] = v;
            }
        }
    }
}

// ---------------------------------------------------------------- big quant GEMM, double-buffered
// Y[N,M] = X[N,K] @ (lut[idx]*scale)^T.  tile 128(N) x 64(M), 256 thr, 8x4 micro.
// N-halves split (ty*4 and 64+ty*4) keeps both Xs reads 2-way (free).
template<int EPI>
__global__ __launch_bounds__(256)
void gemm128_kernel(const float* __restrict__ X, const int* __restrict__ Wi,
                    const float* __restrict__ lut, const float* __restrict__ scale,
                    float* __restrict__ out, int N, int M, int K, int Ttok, int ldo,
                    int qkv_stride) {
    __shared__ float Xs[2][16][132];
    __shared__ float Ws[2][16][68];
    __shared__ float lutl[256];
    int tid = threadIdx.x;
    lutl[tid] = lut[tid];
    int n0 = blockIdx.x * 128, m0 = blockIdx.y * 64;
    int tx = tid & 15, ty = tid >> 4;
    int xnl = tid >> 1, xkq = (tid & 1) * 8;
    int wnl = tid >> 2, wkq = (tid & 3) * 4;
    const float* Xp = X + (size_t)(n0 + xnl) * K + xkq;
    const int*   Wp = Wi + (size_t)(m0 + wnl) * K + wkq;
    float acc[8][4];
#pragma unroll
    for (int i = 0; i < 8; i++)
#pragma unroll
        for (int j = 0; j < 4; j++) acc[i][j] = 0.f;

    // prologue: load + store chunk 0
    float4 xa = *(const float4*)Xp;
    float4 xb = *(const float4*)(Xp + 4);
    int4   iw = *(const int4*)Wp;
    __syncthreads();    // lutl visible
    Xs[0][xkq + 0][xnl] = xa.x; Xs[0][xkq + 1][xnl] = xa.y;
    Xs[0][xkq + 2][xnl] = xa.z; Xs[0][xkq + 3][xnl] = xa.w;
    Xs[0][xkq + 4][xnl] = xb.x; Xs[0][xkq + 5][xnl] = xb.y;
    Xs[0][xkq + 6][xnl] = xb.z; Xs[0][xkq + 7][xnl] = xb.w;
    Ws[0][wkq + 0][wnl] = lutl[iw.x]; Ws[0][wkq + 1][wnl] = lutl[iw.y];
    Ws[0][wkq + 2][wnl] = lutl[iw.z]; Ws[0][wkq + 3][wnl] = lutl[iw.w];

    int nc = K >> 4;
    for (int c = 0; c < nc; c++) {
        int cur = c & 1;
        __syncthreads();          // buf[cur] writes visible; prev readers of buf[cur^1] done
        bool more = (c + 1 < nc);
        if (more) {
            xa = *(const float4*)(Xp + (c + 1) * 16);
            xb = *(const float4*)(Xp + (c + 1) * 16 + 4);
            iw = *(const int4*)(Wp + (c + 1) * 16);
        }
#pragma unroll
        for (int kk = 0; kk < 16; kk++) {
            float4 a0 = *(const float4*)&Xs[cur][kk][ty * 4];
            float4 a1 = *(const float4*)&Xs[cur][kk][64 + ty * 4];
            float4 w  = *(const float4*)&Ws[cur][kk][tx * 4];
            const float* af = (const float*)&a0;
#pragma unroll
            for (int i = 0; i < 4; i++) {
                float av = af[i];
                acc[i][0] = fmaf(av, w.x, acc[i][0]); acc[i][1] = fmaf(av, w.y, acc[i][1]);
                acc[i][2] = fmaf(av, w.z, acc[i][2]); acc[i][3] = fmaf(av, w.w, acc[i][3]);
            }
            const float* bf = (const float*)&a1;
#pragma unroll
            for (int i = 0; i < 4; i++) {
                float av = bf[i];
                acc[4 + i][0] = fmaf(av, w.x, acc[4 + i][0]); acc[4 + i][1] = fmaf(av, w.y, acc[4 + i][1]);
                acc[4 + i][2] = fmaf(av, w.z, acc[4 + i][2]); acc[4 + i][3] = fmaf(av, w.w, acc[4 + i][3]);
            }
        }
        if (more) {
            int nxt = cur ^ 1;
            Xs[nxt][xkq + 0][xnl] = xa.x; Xs[nxt][xkq + 1][xnl] = xa.y;
            Xs[nxt][xkq + 2][xnl] = xa.z; Xs[nxt][xkq + 3][xnl] = xa.w;
            Xs[nxt][xkq + 4][xnl] = xb.x; Xs[nxt][xkq + 5][xnl] = xb.y;
            Xs[nxt][xkq + 6][xnl] = xb.z; Xs[nxt][xkq + 7][xnl] = xb.w;
            Ws[nxt][wkq + 0][wnl] = lutl[iw.x]; Ws[nxt][wkq + 1][wnl] = lutl[iw.y];
            Ws[nxt][wkq + 2][wnl] = lutl[iw.z]; Ws[nxt][wkq + 3][wnl] = lutl[iw.w];
        }
    }

    float4 sc = *(const float4*)&scale[m0 + tx * 4];
    const float* scf = (const float*)&sc;
#pragma unroll
    for (int i = 0; i < 8; i++) {
        int n = n0 + ((i < 4) ? (ty * 4 + i) : (64 + ty * 4 + (i - 4)));
        float4 v;
        float* vf = (float*)&v;
#pragma unroll
        for (int j = 0; j < 4; j++) vf[j] = acc[i][j] * scf[j];
        if (EPI == EPI_STORE) {
            *(float4*)(out + (size_t)n * ldo + m0 + tx * 4) = v;
        } else if (EPI == EPI_ADD) {
            float4* p = (float4*)(out + (size_t)n * ldo + m0 + tx * 4);
            float4 o4 = *p;
            o4.x += v.x; o4.y += v.y; o4.z += v.z; o4.w += v.w;
            *p = o4;
        } else if (EPI == EPI_GELU) {
            v.x = 0.5f * v.x * (1.0f + erff(v.x * 0.70710678118654752f));
            v.y = 0.5f * v.y * (1.0f + erff(v.y * 0.70710678118654752f));
            v.z = 0.5f * v.z * (1.0f + erff(v.z * 0.70710678118654752f));
            v.w = 0.5f * v.w * (1.0f + erff(v.w * 0.70710678118654752f));
            *(float4*)(out + (size_t)n * ldo + m0 + tx * 4) = v;
        } else if (EPI == EPI_QKV) {
            // M = 3*D fused q,k,v; out slot stride qkv_stride floats
            int mat = m0 >> 9;            // m0 / 512
            int h = (m0 >> 6) & 7;
            float* ob = out + (size_t)mat * qkv_stride;
            int b = n / Ttok, t = n - b * Ttok;
            *(float4*)(ob + ((size_t)(b * H_ + h) * Ttok + t) * HD_ + tx * 4) = v;
        }
    }
}

// ---------------------------------------------------------------- flash attention (fp32, LDS-tiled)
template<int TLEN>
__global__ __launch_bounds__(256)
void fattn_kernel(const float* __restrict__ q, const float* __restrict__ k,
                  const float* __restrict__ v, float* __restrict__ o_out) {
    __shared__ float Qs[64][68];     // [row][k]
    __shared__ float KP[64][64];     // Ks: [k][c]  then  Ps: [row][c]
    __shared__ float Vs[64][64];     // [c][d]
    int tid = threadIdx.x;
    int tx = tid & 15, ty = tid >> 4;
    int bh = blockIdx.y;
    int q0 = blockIdx.x * 64;
    const float* Qb = q + ((size_t)bh * TLEN + q0) * HD_;
    const float* Kb = k + (size_t)bh * TLEN * HD_;
    const float* Vb = v + (size_t)bh * TLEN * HD_;
    {
        int r = tid >> 4, f = tid & 15;
#pragma unroll
        for (int it = 0; it < 4; it++) {
            int rr = r + 16 * it;
            float4 t4 = *(const float4*)(Qb + (size_t)rr * HD_ + f * 4);
            *(float4*)&Qs[rr][f * 4] = t4;
        }
    }
    float o[4][4] = {{0.f}};
    float m[4], l[4];
#pragma unroll
    for (int i = 0; i < 4; i++) { m[i] = -3e38f; l[i] = 0.f; }
    __syncthreads();

    for (int c0 = 0; c0 < TLEN; c0 += 64) {
        {
            int c = tid >> 2, fo = tid & 3;
#pragma unroll
            for (int it = 0; it < 4; it++) {
                int f = fo + 4 * it;
                float4 t4 = *(const float4*)(Kb + (size_t)(c0 + c) * HD_ + f * 4);
                KP[f * 4 + 0][c] = t4.x; KP[f * 4 + 1][c] = t4.y;
                KP[f * 4 + 2][c] = t4.z; KP[f * 4 + 3][c] = t4.w;
            }
            int r = tid >> 4, ff = tid & 15;
#pragma unroll
            for (int it = 0; it < 4; it++) {
                int rr = r + 16 * it;
                float4 t4 = *(const float4*)(Vb + (size_t)(c0 + rr) * HD_ + ff * 4);
                *(float4*)&Vs[rr][ff * 4] = t4;
            }
        }
        __syncthreads();
        float s[4][4] = {{0.f}};
        for (int k0 = 0; k0 < 64; k0 += 4) {
            float4 qa[4], kb4[4];
#pragma unroll
            for (int i = 0; i < 4; i++) qa[i] = *(const float4*)&Qs[ty * 4 + i][k0];
#pragma unroll
            for (int kk = 0; kk < 4; kk++) kb4[kk] = *(const float4*)&KP[k0 + kk][tx * 4];
#pragma unroll
            for (int i = 0; i < 4; i++) {
                const float* qf = (const float*)&qa[i];
#pragma unroll
                for (int kk = 0; kk < 4; kk++) {
                    float a = qf[kk];
                    s[i][0] = fmaf(a, kb4[kk].x, s[i][0]);
                    s[i][1] = fmaf(a, kb4[kk].y, s[i][1]);
                    s[i][2] = fmaf(a, kb4[kk].z, s[i][2]);
                    s[i][3] = fmaf(a, kb4[kk].w, s[i][3]);
                }
            }
        }
        __syncthreads();
#pragma unroll
        for (int i = 0; i < 4; i++) {
#pragma unroll
            for (int j = 0; j < 4; j++) s[i][j] *= 0.125f;
            float mx = fmaxf(fmaxf(s[i][0], s[i][1]), fmaxf(s[i][2], s[i][3]));
            mx = fmaxf(mx, __shfl_xor(mx, 1));
            mx = fmaxf(mx, __shfl_xor(mx, 2));
            mx = fmaxf(mx, __shfl_xor(mx, 4));
            mx = fmaxf(mx, __shfl_xor(mx, 8));
            float mn = fmaxf(m[i], mx);
            float f = __expf(m[i] - mn);
            float ps = 0.f;
#pragma unroll
            for (int j = 0; j < 4; j++) { float p = __expf(s[i][j] - mn); s[i][j] = p; ps += p; }
            ps += __shfl_xor(ps, 1);
            ps += __shfl_xor(ps, 2);
            ps += __shfl_xor(ps, 4);
            ps += __shfl_xor(ps, 8);
            l[i] = l[i] * f + ps;
            m[i] = mn;
#pragma unroll
            for (int j = 0; j < 4; j++) o[i][j] *= f;
            *(float4*)&KP[ty * 4 + i][tx * 4] = *(float4*)&s[i][0];
        }
        __syncthreads();
        for (int cc0 = 0; cc0 < 64; cc0 += 4) {
            float4 pa[4], vb4[4];
#pragma unroll
            for (int i = 0; i < 4; i++) pa[i] = *(const float4*)&KP[ty * 4 + i][cc0];
#pragma unroll
            for (int cc = 0; cc < 4; cc++) vb4[cc] = *(const float4*)&Vs[cc0 + cc][tx * 4];
#pragma unroll
            for (int i = 0; i < 4; i++) {
                const float* pf = (const float*)&pa[i];
#pragma unroll
                for (int cc = 0; cc < 4; cc++) {
                    float p = pf[cc];
                    o[i][0] = fmaf(p, vb4[cc].x, o[i][0]);
                    o[i][1] = fmaf(p, vb4[cc].y, o[i][1]);
                    o[i][2] = fmaf(p, vb4[cc].z, o[i][2]);
                    o[i][3] = fmaf(p, vb4[cc].w, o[i][3]);
                }
            }
        }
        __syncthreads();
    }
    int b = bh >> 3, hh = bh & 7;
#pragma unroll
    for (int i = 0; i < 4; i++) {
        float inv = 1.0f / l[i];
        int row = q0 + ty * 4 + i;
        float4 r4;
        r4.x = o[i][0] * inv; r4.y = o[i][1] * inv;
        r4.z = o[i][2] * inv; r4.w = o[i][3] * inv;
        *(float4*)(o_out + ((size_t)(b * TLEN + row)) * D_ + hh * HD_ + tx * 4) = r4;
    }
}

// ---------------------------------------------------------------- conv1d as tiled GEMM, double-buffered
enum { CEPI_NONE = 0, CEPI_RELU = 1, CEPI_TANHBN = 2, CEPI_ADDMEL = 3 };

template<int KW, int IN_TM, int OUT_TM, int EPI>
__global__ __launch_bounds__(256)
void convgemm_kernel(const float* __restrict__ in, const float* __restrict__ w,
                     const float* __restrict__ bias, const float* __restrict__ bng,
                     const float* __restrict__ bnb, const float* __restrict__ meladd,
                     float* __restrict__ out, int Cin, int Cout, int T) {
    constexpr int PAD = KW / 2;
    constexpr int XW = 64 + 2 * PAD;
    constexpr int XTOT = 16 * XW;
    constexpr int NXIT = (XTOT + 255) / 256;
    __shared__ float Xs[2][16][72];
    __shared__ float Ws[2][16 * KW][68];
    int tid = threadIdx.x;
    int tx = tid & 15, ty = tid >> 4;
    int ntile = T >> 6;
    int b = blockIdx.x / ntile, tc = blockIdx.x % ntile;
    int t0 = tc * 64;
    int m0 = blockIdx.y * 64;
    int o_l = tid >> 2, part = tid & 3;
    bool o_ok = (m0 + o_l) < Cout;
    const float* wb = w + (size_t)(m0 + o_l) * Cin * KW;

    float  xreg[NXIT];
    float4 wreg[KW];

    auto load_chunk = [&](int ci0) {
#pragma unroll
        for (int it = 0; it < NXIT; it++) {
            int idx = tid + it * 256;
            float xv = 0.f;
            if (idx < XTOT) {
                int r = idx / XW, ccol = idx - r * XW;
                int t = t0 + ccol - PAD;
                if (t >= 0 && t < T)
                    xv = (IN_TM == 0) ? in[((size_t)(b * Cin + ci0 + r)) * T + t]
                                      : in[((size_t)(b * T + t)) * Cin + ci0 + r];
            }
            xreg[it] = xv;
        }
        const float* wc = wb + (size_t)ci0 * KW;
#pragma unroll
        for (int it = 0; it < KW; it++) {
            int qq = part + it * 4;
            wreg[it] = o_ok ? *(const float4*)(wc + qq * 4) : make_float4(0.f, 0.f, 0.f, 0.f);
        }
    };
    auto store_chunk = [&](int bf) {
#pragma unroll
        for (int it = 0; it < NXIT; it++) {
            int idx = tid + it * 256;
            if (idx < XTOT) {
                int r = idx / XW, ccol = idx - r * XW;
                Xs[bf][r][ccol] = xreg[it];
            }
        }
#pragma unroll
        for (int it = 0; it < KW; it++) {
            int qq = part + it * 4;
            Ws[bf][qq * 4 + 0][o_l] = wreg[it].x; Ws[bf][qq * 4 + 1][o_l] = wreg[it].y;
            Ws[bf][qq * 4 + 2][o_l] = wreg[it].z; Ws[bf][qq * 4 + 3][o_l] = wreg[it].w;
        }
    };

    float acc[4][4];
#pragma unroll
    for (int i = 0; i < 4; i++)
#pragma unroll
        for (int j = 0; j < 4; j++) acc[i][j] = 0.f;

    load_chunk(0);
    store_chunk(0);
    int nc = Cin >> 4;
    for (int c = 0; c < nc; c++) {
        int cur = c & 1;
        __syncthreads();
        bool more = (c + 1 < nc);
        if (more) load_chunk((c + 1) * 16);
#pragma unroll
        for (int kk = 0; kk < 16; kk++) {
            float xr[8];
            float4 xa = *(const float4*)&Xs[cur][kk][tx * 4];
            float4 xb = *(const float4*)&Xs[cur][kk][tx * 4 + 4];
            xr[0] = xa.x; xr[1] = xa.y; xr[2] = xa.z; xr[3] = xa.w;
            xr[4] = xb.x; xr[5] = xb.y; xr[6] = xb.z; xr[7] = xb.w;
#pragma unroll
            for (int k = 0; k < KW; k++) {
                float4 w4 = *(const float4*)&Ws[cur][kk * KW + k][ty * 4];
                const float* wf = (const float*)&w4;
#pragma unroll
                for (int i = 0; i < 4; i++) {
                    float wv = wf[i];
#pragma unroll
                    for (int j = 0; j < 4; j++)
                        acc[i][j] = fmaf(wv, xr[j + k], acc[i][j]);
                }
            }
        }
        if (more) store_chunk((c + 1) & 1);
    }
    // epilogue
    const float inv = 0.99999500003749969f;   // 1/sqrt(1+1e-5)
#pragma unroll
    for (int i = 0; i < 4; i++) {
        int o = m0 + ty * 4 + i;
        if (o >= Cout) continue;
        float bsv = bias[o];
        float g = 0.f, bb = 0.f;
        if (EPI == CEPI_TANHBN) { g = bng[o]; bb = bnb[o]; }
        float vj[4];
#pragma unroll
        for (int j = 0; j < 4; j++) {
            int t = t0 + tx * 4 + j;
            float v = acc[i][j] + bsv;
            if (EPI == CEPI_RELU) {
                v = fmaxf(v, 0.f);
            } else if (EPI == CEPI_TANHBN) {
                float z = v * inv * g + bb;
                z = fminf(fmaxf(z, -15.f), 15.f);
                float e2 = __expf(2.f * z);
                v = (e2 - 1.f) / (e2 + 1.f);
            } else if (EPI == CEPI_ADDMEL) {
                v += meladd[((size_t)(b * T + t)) * NMEL_ + o];
            }
            vj[j] = v;
        }
        if (OUT_TM == 0) {
            float4 v4 = make_float4(vj[0], vj[1], vj[2], vj[3]);
            *(float4*)(out + ((size_t)(b * Cout + o)) * T + t0 + tx * 4) = v4;
        } else {
#pragma unroll
            for (int j = 0; j < 4; j++)
                out[((size_t)(b * T + t0 + tx * 4 + j)) * Cout + o] = vj[j];
        }
    }
}

// ---------------------------------------------------------------- variance-predictor linear (FS -> 1)
__global__ void vplin_kernel(const float* __restrict__ h, const float* __restrict__ lw,
                             const float* __restrict__ lb, float* __restrict__ out, int ntok) {
    int row = blockIdx.x * 4 + (threadIdx.x >> 6);
    int lane = threadIdx.x & 63;
    if (row >= ntok) return;
    const float* hr = h + (size_t)row * FS_;
    float s = 0.f;
    for (int c = lane; c < FS_; c += 64) s += hr[c] * lw[c];
#pragma unroll
    for (int off = 32; off; off >>= 1) s += __shfl_down(s, off);
    if (lane == 0) out[row] = s + lb[0];
}

// ---------------------------------------------------------------- cumsum of durations (per batch)
__global__ void cumsum_kernel(const int* __restrict__ dur, int* __restrict__ cums) {
    __shared__ int c[T_ENC];
    int b = blockIdx.x, tid = threadIdx.x;
    c[tid] = dur[b * T_ENC + tid];
    __syncthreads();
    for (int off = 1; off < T_ENC; off <<= 1) {
        int v = (tid >= off) ? c[tid - off] : 0;
        __syncthreads();
        c[tid] += v;
        __syncthreads();
    }
    cums[b * T_ENC + tid] = c[tid];
}

// ---------------------------------------------------------------- length regulator
__global__ void regulate_kernel(const float* __restrict__ xe, const int* __restrict__ cums,
                                float* __restrict__ xd) {
    int row = blockIdx.x;           // b*ML + f
    int b = row / ML_, f = row % ML_;
    const int* c = cums + b * T_ENC;
    int lo = 0, hi = T_ENC;
    while (lo < hi) { int mid = (lo + hi) >> 1; if (c[mid] <= f) lo = mid + 1; else hi = mid; }
    float valid = (f < c[T_ENC - 1]) ? 1.0f : 0.0f;
    int tok = lo < T_ENC ? lo : T_ENC - 1;
    float4 v = ((const float4*)(xe + ((size_t)(b * T_ENC + tok)) * D_))[threadIdx.x];
    v.x *= valid; v.y *= valid; v.z *= valid; v.w *= valid;
    ((float4*)(xd + (size_t)row * D_))[threadIdx.x] = v;
}

// ---------------------------------------------------------------- x += s*proj_w + proj_b (+ dec_pos)
__global__ void addscale_kernel(float* __restrict__ x, const float* __restrict__ sc,
                                const float* __restrict__ pw, const float* __restrict__ pb,
                                const float* __restrict__ pos) {
    int row = blockIdx.x;           // b*ML + t
    int t = row % ML_;
    float s = sc[row];
    float4* xp = (float4*)(x + (size_t)row * D_);
    float4 v = xp[threadIdx.x];
    float4 w4 = ((const float4*)pw)[threadIdx.x];
    float4 b4 = ((const float4*)pb)[threadIdx.x];
    v.x += s * w4.x + b4.x; v.y += s * w4.y + b4.y;
    v.z += s * w4.z + b4.z; v.w += s * w4.w + b4.w;
    if (pos != nullptr) {
        float4 p4 = ((const float4*)(pos + (size_t)t * D_))[threadIdx.x];
        v.x += p4.x; v.y += p4.y; v.z += p4.z; v.w += p4.w;
    }
    xp[threadIdx.x] = v;
}

// ================================================================ host
extern "C" void kernel_launch(void* const* d_in, const int* in_sizes, int n_in,
                              void* d_out, int out_size, void* d_ws, size_t ws_size,
                              hipStream_t stream) {
    (void)in_sizes; (void)n_in; (void)out_size; (void)ws_size;
    const int*   text = (const int*)d_in[0];
    const int*   durt = (const int*)d_in[1];
    const float* lut  = (const float*)d_in[2];
    const float* emb  = (const float*)d_in[3];
    const float* pos  = (const float*)d_in[4];
    const float* dpos = (const float*)d_in[5];
    const int*   e_ai = (const int*)d_in[6];
    const float* e_as = (const float*)d_in[7];
    const int*   e_ui = (const int*)d_in[8];
    const float* e_us = (const float*)d_in[9];
    const int*   e_di = (const int*)d_in[10];
    const float* e_ds = (const float*)d_in[11];
    const float* e_g  = (const float*)d_in[12];
    const float* e_b  = (const float*)d_in[13];
    const int*   d_ai = (const int*)d_in[14];
    const float* d_as = (const float*)d_in[15];
    const int*   d_ui = (const int*)d_in[16];
    const float* d_us = (const float*)d_in[17];
    const int*   d_di = (const int*)d_in[18];
    const float* d_ds = (const float*)d_in[19];
    const float* d_g  = (const float*)d_in[20];
    const float* d_b  = (const float*)d_in[21];
    const float* vp_c1w = (const float*)d_in[22];
    const float* vp_c1b = (const float*)d_in[23];
    const float* vp_g1  = (const float*)d_in[24];
    const float* vp_b1  = (const float*)d_in[25];
    const float* vp_c2w = (const float*)d_in[26];
    const float* vp_c2b = (const float*)d_in[27];
    const float* vp_g2  = (const float*)d_in[28];
    const float* vp_b2  = (const float*)d_in[29];
    const float* vp_lw  = (const float*)d_in[30];
    const float* vp_lb  = (const float*)d_in[31];
    const float* proj_w = (const float*)d_in[32];
    const float* proj_b = (const float*)d_in[33];
    const float* mel_w  = (const float*)d_in[34];
    const float* mel_b  = (const float*)d_in[35];
    const float* pn_w[5] = {(const float*)d_in[36], (const float*)d_in[38], (const float*)d_in[40],
                            (const float*)d_in[42], (const float*)d_in[44]};
    const float* pn_bv[5] = {(const float*)d_in[37], (const float*)d_in[39], (const float*)d_in[41],
                             (const float*)d_in[43], (const float*)d_in[45]};
    const float* pn_g  = (const float*)d_in[46];
    const float* pn_bb = (const float*)d_in[47];

    float* ws = (float*)d_ws;
    float* xe  = ws;                        // [4,512,512]
    float* xd  = ws + 1048576;              // [4,1024,512]
    float* h   = ws + 3145728;              // [4,1024,512]
    float* qb  = ws + 5242880;              // [4,8,1024,64]  (kb, vb follow at QKVSTRIDE_)
    float* kb  = ws + 7340032;
    float* vb  = ws + 9437184;
    float* ob  = ws + 11534336;             // [4,1024,512]
    float* hff = ws + 13631488;             // [4,1024,2048]
    float* vp1 = ws + 22020096;             // [4,1024,256]
    float* vp2 = ws + 23068672;
    int*   cums = (int*)(ws + 24117248);    // [4,512]
    float* pn_a = ws + 24119296;            // [4,512,1024]
    float* pn_b2f = ws + 26216448;

    float* outp   = (float*)d_out;
    float* mel    = outp;                   // [4,1024,80]
    float* melp   = outp + 327680;
    float* durp   = outp + 655360;          // [4,512]
    float* pitch  = outp + 657408;          // [4,1024]
    float* energy = outp + 661504;

    embed_kernel<<<B_ * T_ENC, 128, 0, stream>>>(text, emb, pos, xe);

    auto run_block = [&](float* x, int T, int N, const int* ai, const float* as,
                         const int* ui, const float* us, const int* di, const float* ds,
                         const float* g, const float* bv) {
        ln_kernel<<<N, 256, 0, stream>>>(x, g, bv, h, D_);
        dim3 gq3(N / 128, 24);   // fused q,k,v: M = 1536
        gemm128_kernel<EPI_QKV><<<gq3, 256, 0, stream>>>(h, ai, lut, as, qb, N, 3 * D_, D_, T, 0, QKVSTRIDE_);
        if (T == T_ENC) fattn_kernel<512><<<dim3(512 / 64, B_ * H_), 256, 0, stream>>>(qb, kb, vb, ob);
        else            fattn_kernel<1024><<<dim3(1024 / 64, B_ * H_), 256, 0, stream>>>(qb, kb, vb, ob);
        dim3 go(N / 128, D_ / 64);
        gemm128_kernel<EPI_ADD><<<go, 256, 0, stream>>>(ob, ai + 3 * D_ * D_, lut, as + 3 * D_, x, N, D_, D_, 0, D_, 0);
        ln_kernel<<<N, 256, 0, stream>>>(x, g + D_, bv + D_, h, D_);
        dim3 gu(N / 128, FF_ / 64);
        gemm128_kernel<EPI_GELU><<<gu, 256, 0, stream>>>(h, ui, lut, us, hff, N, FF_, D_, 0, FF_, 0);
        dim3 gd(N / 128, D_ / 64);
        gemm128_kernel<EPI_ADD><<<gd, 256, 0, stream>>>(hff, di, lut, ds, x, N, D_, FF_, 0, D_, 0);
    };

    for (int l = 0; l < L_; l++)
        run_block(xe, T_ENC, B_ * T_ENC,
                  e_ai + (size_t)l * 4 * D_ * D_, e_as + (size_t)l * 4 * D_,
                  e_ui + (size_t)l * FF_ * D_,    e_us + (size_t)l * FF_,
                  e_di + (size_t)l * D_ * FF_,    e_ds + (size_t)l * D_,
                  e_g + (size_t)l * 2 * D_,       e_b + (size_t)l * 2 * D_);

    auto run_varpred = [&](const float* x, int T, int j, float* out) {
        int N = B_ * T;
        dim3 gc1(B_ * (T / 64), FS_ / 64);
        convgemm_kernel<3, 1, 1, CEPI_RELU><<<gc1, 256, 0, stream>>>(
            x, vp_c1w + (size_t)j * FS_ * D_ * 3, vp_c1b + j * FS_, nullptr, nullptr, nullptr,
            vp1, D_, FS_, T);
        ln_kernel<<<N, 256, 0, stream>>>(vp1, vp_g1 + j * FS_, vp_b1 + j * FS_, vp2, FS_);
        convgemm_kernel<3, 1, 1, CEPI_RELU><<<gc1, 256, 0, stream>>>(
            vp2, vp_c2w + (size_t)j * FS_ * FS_ * 3, vp_c2b + j * FS_, nullptr, nullptr, nullptr,
            vp1, FS_, FS_, T);
        ln_kernel<<<N, 256, 0, stream>>>(vp1, vp_g2 + j * FS_, vp_b2 + j * FS_, vp2, FS_);
        vplin_kernel<<<N / 4, 256, 0, stream>>>(vp2, vp_lw + j * FS_, vp_lb + j, out, N);
    };

    run_varpred(xe, T_ENC, 0, durp);

    cumsum_kernel<<<B_, T_ENC, 0, stream>>>(durt, cums);
    regulate_kernel<<<B_ * ML_, 128, 0, stream>>>(xe, cums, xd);

    run_varpred(xd, ML_, 1, pitch);
    addscale_kernel<<<B_ * ML_, 128, 0, stream>>>(xd, pitch, proj_w, proj_b, nullptr);
    run_varpred(xd, ML_, 2, energy);
    addscale_kernel<<<B_ * ML_, 128, 0, stream>>>(xd, energy, proj_w + D_, proj_b + D_, dpos);

    for (int l = 0; l < L_; l++)
        run_block(xd, ML_, B_ * ML_,
                  d_ai + (size_t)l * 4 * D_ * D_, d_as + (size_t)l * 4 * D_,
                  d_ui + (size_t)l * FF_ * D_,    d_us + (size_t)l * FF_,
                  d_di + (size_t)l * D_ * FF_,    d_ds + (size_t)l * D_,
                  d_g + (size_t)l * 2 * D_,       d_b + (size_t)l * 2 * D_);

    {
        dim3 gm((B_ * ML_) / 64, (NMEL_ + 63) / 64);
        gemm_kernel<EPI_BIAS, false><<<gm, 256, 0, stream>>>(xd, mel_w, nullptr, nullptr, mel_b,
                                                             mel, B_ * ML_, NMEL_, D_, 0, NMEL_);
    }

    {
        dim3 g1(B_ * (ML_ / 64), PN_ / 64);
        convgemm_kernel<5, 1, 0, CEPI_TANHBN><<<g1, 256, 0, stream>>>(
            mel, pn_w[0], pn_bv[0], pn_g, pn_bb, nullptr, pn_a, NMEL_, PN_, ML_);
        convgemm_kernel<5, 0, 0, CEPI_TANHBN><<<g1, 256, 0, stream>>>(
            pn_a, pn_w[1], pn_bv[1], pn_g + PN_, pn_bb + PN_, nullptr, pn_b2f, PN_, PN_, ML_);
        convgemm_kernel<5, 0, 0, CEPI_TANHBN><<<g1, 256, 0, stream>>>(
            pn_b2f, pn_w[2], pn_bv[2], pn_g + 2 * PN_, pn_bb + 2 * PN_, nullptr, pn_a, PN_, PN_, ML_);
        convgemm_kernel<5, 0, 0, CEPI_TANHBN><<<g1, 256, 0, stream>>>(
            pn_a, pn_w[3], pn_bv[3], pn_g + 3 * PN_, pn_bb + 3 * PN_, nullptr, pn_b2f, PN_, PN_, ML_);
        dim3 g5(B_ * (ML_ / 64), (NMEL_ + 63) / 64);
        convgemm_kernel<5, 0, 1, CEPI_ADDMEL><<<g5, 256, 0, stream>>>(
            pn_b2f, pn_w[4], pn_bv[4], nullptr, nullptr, mel, melp, PN_, NMEL_, ML_);
    }
}

// Round 5
// 6578.187 us; speedup vs baseline: 1.0172x; 1.0172x over previous
//
#include <hip/hip_runtime.h>
#include <math.h>

#define B_    4
#define T_ENC 512
#define ML_   1024
#define D_    512
#define H_    8
#define HD_   64
#define FF_   2048
#define FS_   256
#define NMEL_ 80
#define PN_   512
#define L_    4
#define QKVSTRIDE_ 2097152

// ---------------------------------------------------------------- embed
__global__ void embed_kernel(const int* __restrict__ text, const float* __restrict__ emb,
                             const float* __restrict__ pos, float* __restrict__ x) {
    int row = blockIdx.x;            // b*T + t
    int t = row % T_ENC;
    int tok = text[row];
    float4 e = ((const float4*)(emb + (size_t)tok * D_))[threadIdx.x];
    float4 p = ((const float4*)(pos + (size_t)t * D_))[threadIdx.x];
    e.x += p.x; e.y += p.y; e.z += p.z; e.w += p.w;
    ((float4*)(x + (size_t)row * D_))[threadIdx.x] = e;
}

// ---------------------------------------------------------------- layernorm: wave per row, shuffle reduce
__global__ __launch_bounds__(256)
void ln_kernel(const float* __restrict__ x, const float* __restrict__ g,
               const float* __restrict__ b, float* __restrict__ out, int D) {
    int row = blockIdx.x * 4 + (threadIdx.x >> 6);
    int lane = threadIdx.x & 63;
    const float* xr = x + (size_t)row * D;
    float4 vals[2];
    int nit = D >> 8;                // D=512 -> 2, D=256 -> 1
    float s = 0.f, q = 0.f;
#pragma unroll 2
    for (int it = 0; it < nit; it++) {
        float4 v = ((const float4*)xr)[lane + it * 64];
        vals[it] = v;
        s += v.x + v.y + v.z + v.w;
        q += v.x * v.x + v.y * v.y + v.z * v.z + v.w * v.w;
    }
#pragma unroll
    for (int off = 32; off; off >>= 1) {
        s += __shfl_xor(s, off);
        q += __shfl_xor(q, off);
    }
    float mean = s / D;
    float var  = q / D - mean * mean;
    float rstd = rsqrtf(var + 1e-5f);
    float* orow = out + (size_t)row * D;
#pragma unroll 2
    for (int it = 0; it < nit; it++) {
        int d4 = lane + it * 64;
        float4 gv = ((const float4*)g)[d4];
        float4 bv = ((const float4*)b)[d4];
        float4 v = vals[it];
        v.x = (v.x - mean) * rstd * gv.x + bv.x;
        v.y = (v.y - mean) * rstd * gv.y + bv.y;
        v.z = (v.z - mean) * rstd * gv.z + bv.z;
        v.w = (v.w - mean) * rstd * gv.w + bv.w;
        ((float4*)orow)[d4] = v;
    }
}

// ---------------------------------------------------------------- small GEMM (kept for mel proj)
enum { EPI_STORE = 0, EPI_ADD = 1, EPI_GELU = 2, EPI_QKV = 3, EPI_BIAS = 4 };

template<int EPI, bool QUANT>
__global__ __launch_bounds__(256)
void gemm_kernel(const float* __restrict__ X, const void* __restrict__ Wv,
                 const float* __restrict__ lut, const float* __restrict__ scale,
                 const float* __restrict__ bias, float* __restrict__ out,
                 int N, int M, int K, int Ttok, int ldo) {
    __shared__ float Xs[16][68];
    __shared__ float Ws[16][68];
    int tid = threadIdx.x;
    int n0 = blockIdx.x * 64, m0 = blockIdx.y * 64;
    int tx = tid & 15, ty = tid >> 4;
    int nl = tid >> 2, kq = (tid & 3) * 4;
    const float* Xp = X + (size_t)(n0 + nl) * K + kq;
    const float* Wf = (const float*)Wv;
    size_t wrow = (size_t)(m0 + nl) * K + kq;
    bool wok = (m0 + nl) < M;
    float c[4][4] = {{0.f}};
    for (int k0 = 0; k0 < K; k0 += 16) {
        __syncthreads();
        float4 xv = *(const float4*)(Xp + k0);
        float w0, w1, w2, w3;
        if (wok) {
            float4 w4 = *(const float4*)(Wf + wrow + k0);
            w0 = w4.x; w1 = w4.y; w2 = w4.z; w3 = w4.w;
        } else { w0 = w1 = w2 = w3 = 0.f; }
        Xs[kq + 0][nl] = xv.x; Xs[kq + 1][nl] = xv.y; Xs[kq + 2][nl] = xv.z; Xs[kq + 3][nl] = xv.w;
        Ws[kq + 0][nl] = w0;   Ws[kq + 1][nl] = w1;   Ws[kq + 2][nl] = w2;   Ws[kq + 3][nl] = w3;
        __syncthreads();
#pragma unroll
        for (int kk = 0; kk < 16; kk++) {
            float4 a = *(const float4*)&Xs[kk][ty * 4];
            float4 w = *(const float4*)&Ws[kk][tx * 4];
            c[0][0] = fmaf(a.x, w.x, c[0][0]); c[0][1] = fmaf(a.x, w.y, c[0][1]);
            c[0][2] = fmaf(a.x, w.z, c[0][2]); c[0][3] = fmaf(a.x, w.w, c[0][3]);
            c[1][0] = fmaf(a.y, w.x, c[1][0]); c[1][1] = fmaf(a.y, w.y, c[1][1]);
            c[1][2] = fmaf(a.y, w.z, c[1][2]); c[1][3] = fmaf(a.y, w.w, c[1][3]);
            c[2][0] = fmaf(a.z, w.x, c[2][0]); c[2][1] = fmaf(a.z, w.y, c[2][1]);
            c[2][2] = fmaf(a.z, w.z, c[2][2]); c[2][3] = fmaf(a.z, w.w, c[2][3]);
            c[3][0] = fmaf(a.w, w.x, c[3][0]); c[3][1] = fmaf(a.w, w.y, c[3][1]);
            c[3][2] = fmaf(a.w, w.z, c[3][2]); c[3][3] = fmaf(a.w, w.w, c[3][3]);
        }
    }
#pragma unroll
    for (int i = 0; i < 4; i++) {
        int n = n0 + ty * 4 + i;
#pragma unroll
        for (int j = 0; j < 4; j++) {
            int m = m0 + tx * 4 + j;
            float v = c[i][j];
            if (EPI == EPI_BIAS) {
                if (m < M) out[(size_t)n * ldo + m] = v + bias[m];
            } else if (EPI == EPI_STORE) {
                if (m < M) out[(size_t)n * ldo + m] = v;
            }
        }
    }
}

// ---------------------------------------------------------------- big quant GEMM, double-buffered
template<int EPI>
__global__ __launch_bounds__(256)
void gemm128_kernel(const float* __restrict__ X, const int* __restrict__ Wi,
                    const float* __restrict__ lut, const float* __restrict__ scale,
                    float* __restrict__ out, int N, int M, int K, int Ttok, int ldo,
                    int qkv_stride) {
    __shared__ float Xs[2][16][132];
    __shared__ float Ws[2][16][68];
    __shared__ float lutl[256];
    int tid = threadIdx.x;
    lutl[tid] = lut[tid];
    int n0 = blockIdx.x * 128, m0 = blockIdx.y * 64;
    int tx = tid & 15, ty = tid >> 4;
    int xnl = tid >> 1, xkq = (tid & 1) * 8;
    int wnl = tid >> 2, wkq = (tid & 3) * 4;
    const float* Xp = X + (size_t)(n0 + xnl) * K + xkq;
    const int*   Wp = Wi + (size_t)(m0 + wnl) * K + wkq;
    float acc[8][4];
#pragma unroll
    for (int i = 0; i < 8; i++)
#pragma unroll
        for (int j = 0; j < 4; j++) acc[i][j] = 0.f;

    float4 xa = *(const float4*)Xp;
    float4 xb = *(const float4*)(Xp + 4);
    int4   iw = *(const int4*)Wp;
    __syncthreads();    // lutl visible
    Xs[0][xkq + 0][xnl] = xa.x; Xs[0][xkq + 1][xnl] = xa.y;
    Xs[0][xkq + 2][xnl] = xa.z; Xs[0][xkq + 3][xnl] = xa.w;
    Xs[0][xkq + 4][xnl] = xb.x; Xs[0][xkq + 5][xnl] = xb.y;
    Xs[0][xkq + 6][xnl] = xb.z; Xs[0][xkq + 7][xnl] = xb.w;
    Ws[0][wkq + 0][wnl] = lutl[iw.x]; Ws[0][wkq + 1][wnl] = lutl[iw.y];
    Ws[0][wkq + 2][wnl] = lutl[iw.z]; Ws[0][wkq + 3][wnl] = lutl[iw.w];

    int nc = K >> 4;
    for (int c = 0; c < nc; c++) {
        int cur = c & 1;
        __syncthreads();
        bool more = (c + 1 < nc);
        if (more) {
            xa = *(const float4*)(Xp + (c + 1) * 16);
            xb = *(const float4*)(Xp + (c + 1) * 16 + 4);
            iw = *(const int4*)(Wp + (c + 1) * 16);
        }
#pragma unroll
        for (int kk = 0; kk < 16; kk++) {
            float4 a0 = *(const float4*)&Xs[cur][kk][ty * 4];
            float4 a1 = *(const float4*)&Xs[cur][kk][64 + ty * 4];
            float4 w  = *(const float4*)&Ws[cur][kk][tx * 4];
            const float* af = (const float*)&a0;
#pragma unroll
            for (int i = 0; i < 4; i++) {
                float av = af[i];
                acc[i][0] = fmaf(av, w.x, acc[i][0]); acc[i][1] = fmaf(av, w.y, acc[i][1]);
                acc[i][2] = fmaf(av, w.z, acc[i][2]); acc[i][3] = fmaf(av, w.w, acc[i][3]);
            }
            const float* bf = (const float*)&a1;
#pragma unroll
            for (int i = 0; i < 4; i++) {
                float av = bf[i];
                acc[4 + i][0] = fmaf(av, w.x, acc[4 + i][0]); acc[4 + i][1] = fmaf(av, w.y, acc[4 + i][1]);
                acc[4 + i][2] = fmaf(av, w.z, acc[4 + i][2]); acc[4 + i][3] = fmaf(av, w.w, acc[4 + i][3]);
            }
        }
        if (more) {
            int nxt = cur ^ 1;
            Xs[nxt][xkq + 0][xnl] = xa.x; Xs[nxt][xkq + 1][xnl] = xa.y;
            Xs[nxt][xkq + 2][xnl] = xa.z; Xs[nxt][xkq + 3][xnl] = xa.w;
            Xs[nxt][xkq + 4][xnl] = xb.x; Xs[nxt][xkq + 5][xnl] = xb.y;
            Xs[nxt][xkq + 6][xnl] = xb.z; Xs[nxt][xkq + 7][xnl] = xb.w;
            Ws[nxt][wkq + 0][wnl] = lutl[iw.x]; Ws[nxt][wkq + 1][wnl] = lutl[iw.y];
            Ws[nxt][wkq + 2][wnl] = lutl[iw.z]; Ws[nxt][wkq + 3][wnl] = lutl[iw.w];
        }
    }

    float4 sc = *(const float4*)&scale[m0 + tx * 4];
    const float* scf = (const float*)&sc;
#pragma unroll
    for (int i = 0; i < 8; i++) {
        int n = n0 + ((i < 4) ? (ty * 4 + i) : (64 + ty * 4 + (i - 4)));
        float4 v;
        float* vf = (float*)&v;
#pragma unroll
        for (int j = 0; j < 4; j++) vf[j] = acc[i][j] * scf[j];
        if (EPI == EPI_STORE) {
            *(float4*)(out + (size_t)n * ldo + m0 + tx * 4) = v;
        } else if (EPI == EPI_ADD) {
            float4* p = (float4*)(out + (size_t)n * ldo + m0 + tx * 4);
            float4 o4 = *p;
            o4.x += v.x; o4.y += v.y; o4.z += v.z; o4.w += v.w;
            *p = o4;
        } else if (EPI == EPI_GELU) {
            v.x = 0.5f * v.x * (1.0f + erff(v.x * 0.70710678118654752f));
            v.y = 0.5f * v.y * (1.0f + erff(v.y * 0.70710678118654752f));
            v.z = 0.5f * v.z * (1.0f + erff(v.z * 0.70710678118654752f));
            v.w = 0.5f * v.w * (1.0f + erff(v.w * 0.70710678118654752f));
            *(float4*)(out + (size_t)n * ldo + m0 + tx * 4) = v;
        } else if (EPI == EPI_QKV) {
            int mat = m0 >> 9;
            int h = (m0 >> 6) & 7;
            float* ob = out + (size_t)mat * qkv_stride;
            int b = n / Ttok, t = n - b * Ttok;
            *(float4*)(ob + ((size_t)(b * H_ + h) * Ttok + t) * HD_ + tx * 4) = v;
        }
    }
}

// ---------------------------------------------------------------- flash attention (fp32, LDS-tiled)
template<int TLEN>
__global__ __launch_bounds__(256)
void fattn_kernel(const float* __restrict__ q, const float* __restrict__ k,
                  const float* __restrict__ v, float* __restrict__ o_out) {
    __shared__ float Qs[64][68];
    __shared__ float KP[64][64];
    __shared__ float Vs[64][64];
    int tid = threadIdx.x;
    int tx = tid & 15, ty = tid >> 4;
    int bh = blockIdx.y;
    int q0 = blockIdx.x * 64;
    const float* Qb = q + ((size_t)bh * TLEN + q0) * HD_;
    const float* Kb = k + (size_t)bh * TLEN * HD_;
    const float* Vb = v + (size_t)bh * TLEN * HD_;
    {
        int r = tid >> 4, f = tid & 15;
#pragma unroll
        for (int it = 0; it < 4; it++) {
            int rr = r + 16 * it;
            float4 t4 = *(const float4*)(Qb + (size_t)rr * HD_ + f * 4);
            *(float4*)&Qs[rr][f * 4] = t4;
        }
    }
    float o[4][4] = {{0.f}};
    float m[4], l[4];
#pragma unroll
    for (int i = 0; i < 4; i++) { m[i] = -3e38f; l[i] = 0.f; }
    __syncthreads();

    for (int c0 = 0; c0 < TLEN; c0 += 64) {
        {
            int c = tid >> 2, fo = tid & 3;
#pragma unroll
            for (int it = 0; it < 4; it++) {
                int f = fo + 4 * it;
                float4 t4 = *(const float4*)(Kb + (size_t)(c0 + c) * HD_ + f * 4);
                KP[f * 4 + 0][c] = t4.x; KP[f * 4 + 1][c] = t4.y;
                KP[f * 4 + 2][c] = t4.z; KP[f * 4 + 3][c] = t4.w;
            }
            int r = tid >> 4, ff = tid & 15;
#pragma unroll
            for (int it = 0; it < 4; it++) {
                int rr = r + 16 * it;
                float4 t4 = *(const float4*)(Vb + (size_t)(c0 + rr) * HD_ + ff * 4);
                *(float4*)&Vs[rr][ff * 4] = t4;
            }
        }
        __syncthreads();
        float s[4][4] = {{0.f}};
        for (int k0 = 0; k0 < 64; k0 += 4) {
            float4 qa[4], kb4[4];
#pragma unroll
            for (int i = 0; i < 4; i++) qa[i] = *(const float4*)&Qs[ty * 4 + i][k0];
#pragma unroll
            for (int kk = 0; kk < 4; kk++) kb4[kk] = *(const float4*)&KP[k0 + kk][tx * 4];
#pragma unroll
            for (int i = 0; i < 4; i++) {
                const float* qf = (const float*)&qa[i];
#pragma unroll
                for (int kk = 0; kk < 4; kk++) {
                    float a = qf[kk];
                    s[i][0] = fmaf(a, kb4[kk].x, s[i][0]);
                    s[i][1] = fmaf(a, kb4[kk].y, s[i][1]);
                    s[i][2] = fmaf(a, kb4[kk].z, s[i][2]);
                    s[i][3] = fmaf(a, kb4[kk].w, s[i][3]);
                }
            }
        }
        __syncthreads();
#pragma unroll
        for (int i = 0; i < 4; i++) {
#pragma unroll
            for (int j = 0; j < 4; j++) s[i][j] *= 0.125f;
            float mx = fmaxf(fmaxf(s[i][0], s[i][1]), fmaxf(s[i][2], s[i][3]));
            mx = fmaxf(mx, __shfl_xor(mx, 1));
            mx = fmaxf(mx, __shfl_xor(mx, 2));
            mx = fmaxf(mx, __shfl_xor(mx, 4));
            mx = fmaxf(mx, __shfl_xor(mx, 8));
            float mn = fmaxf(m[i], mx);
            float f = __expf(m[i] - mn);
            float ps = 0.f;
#pragma unroll
            for (int j = 0; j < 4; j++) { float p = __expf(s[i][j] - mn); s[i][j] = p; ps += p; }
            ps += __shfl_xor(ps, 1);
            ps += __shfl_xor(ps, 2);
            ps += __shfl_xor(ps, 4);
            ps += __shfl_xor(ps, 8);
            l[i] = l[i] * f + ps;
            m[i] = mn;
#pragma unroll
            for (int j = 0; j < 4; j++) o[i][j] *= f;
            *(float4*)&KP[ty * 4 + i][tx * 4] = *(float4*)&s[i][0];
        }
        __syncthreads();
        for (int cc0 = 0; cc0 < 64; cc0 += 4) {
            float4 pa[4], vb4[4];
#pragma unroll
            for (int i = 0; i < 4; i++) pa[i] = *(const float4*)&KP[ty * 4 + i][cc0];
#pragma unroll
            for (int cc = 0; cc < 4; cc++) vb4[cc] = *(const float4*)&Vs[cc0 + cc][tx * 4];
#pragma unroll
            for (int i = 0; i < 4; i++) {
                const float* pf = (const float*)&pa[i];
#pragma unroll
                for (int cc = 0; cc < 4; cc++) {
                    float p = pf[cc];
                    o[i][0] = fmaf(p, vb4[cc].x, o[i][0]);
                    o[i][1] = fmaf(p, vb4[cc].y, o[i][1]);
                    o[i][2] = fmaf(p, vb4[cc].z, o[i][2]);
                    o[i][3] = fmaf(p, vb4[cc].w, o[i][3]);
                }
            }
        }
        __syncthreads();
    }
    int b = bh >> 3, hh = bh & 7;
#pragma unroll
    for (int i = 0; i < 4; i++) {
        float inv = 1.0f / l[i];
        int row = q0 + ty * 4 + i;
        float4 r4;
        r4.x = o[i][0] * inv; r4.y = o[i][1] * inv;
        r4.z = o[i][2] * inv; r4.w = o[i][3] * inv;
        *(float4*)(o_out + ((size_t)(b * TLEN + row)) * D_ + hh * HD_ + tx * 4) = r4;
    }
}

// ---------------------------------------------------------------- conv1d as tiled GEMM
// 128 threads; tile 64 t x 64 oc; per-thread 8t x 4oc. single-buffered LDS.
enum { CEPI_NONE = 0, CEPI_RELU = 1, CEPI_TANHBN = 2, CEPI_ADDMEL = 3 };

template<int KW, int IN_TM, int OUT_TM, int EPI>
__global__ __launch_bounds__(128)
void convgemm_kernel(const float* __restrict__ in, const float* __restrict__ w,
                     const float* __restrict__ bias, const float* __restrict__ bng,
                     const float* __restrict__ bnb, const float* __restrict__ meladd,
                     float* __restrict__ out, int Cin, int Cout, int T) {
    constexpr int PAD = KW / 2;
    constexpr int XW = 64 + 2 * PAD;          // 66 (KW3) or 68 (KW5)
    constexpr int XTOT = 16 * XW;
    __shared__ float Xs[16][72];
    __shared__ float Ws[16 * KW][68];
    int tid = threadIdx.x;                     // 0..127
    int tx = tid & 7;                          // 8 time groups of 8
    int ty = tid >> 3;                         // 16 oc groups of 4
    int ntile = T >> 6;
    int b = blockIdx.x / ntile, tc = blockIdx.x % ntile;
    int t0 = tc * 64;
    int m0 = blockIdx.y * 64;
    int o_l = tid >> 1, part = tid & 1;        // weight staging: 2 threads per oc
    bool o_ok = (m0 + o_l) < Cout;
    const float* wb = w + (size_t)(m0 + o_l) * Cin * KW;

    float acc[4][8];
#pragma unroll
    for (int i = 0; i < 4; i++)
#pragma unroll
        for (int j = 0; j < 8; j++) acc[i][j] = 0.f;

    for (int ci0 = 0; ci0 < Cin; ci0 += 16) {
        __syncthreads();
        // stage weights: Ws[ci*KW+k][o] ; per oc the chunk is 16*KW consecutive floats
        {
            const float* wc = wb + (size_t)ci0 * KW;
#pragma unroll
            for (int it = 0; it < 2 * KW; it++) {
                int qq = part + it * 2;        // float4 index within 4*KW
                float4 t4 = o_ok ? *(const float4*)(wc + qq * 4)
                                 : make_float4(0.f, 0.f, 0.f, 0.f);
                Ws[qq * 4 + 0][o_l] = t4.x; Ws[qq * 4 + 1][o_l] = t4.y;
                Ws[qq * 4 + 2][o_l] = t4.z; Ws[qq * 4 + 3][o_l] = t4.w;
            }
        }
        // stage input tile with halo
        for (int idx = tid; idx < XTOT; idx += 128) {
            int r = idx / XW, ccol = idx - r * XW;
            int t = t0 + ccol - PAD;
            float xv = 0.f;
            if (t >= 0 && t < T)
                xv = (IN_TM == 0) ? in[((size_t)(b * Cin + ci0 + r)) * T + t]
                                  : in[((size_t)(b * T + t)) * Cin + ci0 + r];
            Xs[r][ccol] = xv;
        }
        __syncthreads();
#pragma unroll
        for (int kk = 0; kk < 16; kk++) {
            float xr[12];
            float4 x0 = *(const float4*)&Xs[kk][tx * 8];
            float4 x1 = *(const float4*)&Xs[kk][tx * 8 + 4];
            float4 x2 = *(const float4*)&Xs[kk][tx * 8 + 8];
            xr[0] = x0.x; xr[1] = x0.y; xr[2]  = x0.z; xr[3]  = x0.w;
            xr[4] = x1.x; xr[5] = x1.y; xr[6]  = x1.z; xr[7]  = x1.w;
            xr[8] = x2.x; xr[9] = x2.y; xr[10] = x2.z; xr[11] = x2.w;
#pragma unroll
            for (int k = 0; k < KW; k++) {
                float4 w4 = *(const float4*)&Ws[kk * KW + k][ty * 4];
                const float* wf = (const float*)&w4;
#pragma unroll
                for (int i = 0; i < 4; i++) {
                    float wv = wf[i];
#pragma unroll
                    for (int j = 0; j < 8; j++)
                        acc[i][j] = fmaf(wv, xr[j + k], acc[i][j]);
                }
            }
        }
    }
    // epilogue
    const float inv = 0.99999500003749969f;   // 1/sqrt(1+1e-5)
#pragma unroll
    for (int i = 0; i < 4; i++) {
        int o = m0 + ty * 4 + i;
        if (o >= Cout) continue;
        float bsv = bias[o];
        float g = 0.f, bb = 0.f;
        if (EPI == CEPI_TANHBN) { g = bng[o]; bb = bnb[o]; }
        float vj[8];
#pragma unroll
        for (int j = 0; j < 8; j++) {
            int t = t0 + tx * 8 + j;
            float v = acc[i][j] + bsv;
            if (EPI == CEPI_RELU) {
                v = fmaxf(v, 0.f);
            } else if (EPI == CEPI_TANHBN) {
                float z = v * inv * g + bb;
                z = fminf(fmaxf(z, -15.f), 15.f);
                float e2 = __expf(2.f * z);
                v = (e2 - 1.f) / (e2 + 1.f);
            } else if (EPI == CEPI_ADDMEL) {
                v += meladd[((size_t)(b * T + t)) * NMEL_ + o];
            }
            vj[j] = v;
        }
        if (OUT_TM == 0) {
            *(float4*)(out + ((size_t)(b * Cout + o)) * T + t0 + tx * 8) =
                make_float4(vj[0], vj[1], vj[2], vj[3]);
            *(float4*)(out + ((size_t)(b * Cout + o)) * T + t0 + tx * 8 + 4) =
                make_float4(vj[4], vj[5], vj[6], vj[7]);
        } else {
#pragma unroll
            for (int j = 0; j < 8; j++)
                out[((size_t)(b * T + t0 + tx * 8 + j)) * Cout + o] = vj[j];
        }
    }
}

// ---------------------------------------------------------------- variance-predictor linear (FS -> 1)
__global__ void vplin_kernel(const float* __restrict__ h, const float* __restrict__ lw,
                             const float* __restrict__ lb, float* __restrict__ out, int ntok) {
    int row = blockIdx.x * 4 + (threadIdx.x >> 6);
    int lane = threadIdx.x & 63;
    if (row >= ntok) return;
    const float* hr = h + (size_t)row * FS_;
    float s = 0.f;
    for (int c = lane; c < FS_; c += 64) s += hr[c] * lw[c];
#pragma unroll
    for (int off = 32; off; off >>= 1) s += __shfl_down(s, off);
    if (lane == 0) out[row] = s + lb[0];
}

// ---------------------------------------------------------------- cumsum of durations (per batch)
__global__ void cumsum_kernel(const int* __restrict__ dur, int* __restrict__ cums) {
    __shared__ int c[T_ENC];
    int b = blockIdx.x, tid = threadIdx.x;
    c[tid] = dur[b * T_ENC + tid];
    __syncthreads();
    for (int off = 1; off < T_ENC; off <<= 1) {
        int v = (tid >= off) ? c[tid - off] : 0;
        __syncthreads();
        c[tid] += v;
        __syncthreads();
    }
    cums[b * T_ENC + tid] = c[tid];
}

// ---------------------------------------------------------------- length regulator
__global__ void regulate_kernel(const float* __restrict__ xe, const int* __restrict__ cums,
                                float* __restrict__ xd) {
    int row = blockIdx.x;           // b*ML + f
    int b = row / ML_, f = row % ML_;
    const int* c = cums + b * T_ENC;
    int lo = 0, hi = T_ENC;
    while (lo < hi) { int mid = (lo + hi) >> 1; if (c[mid] <= f) lo = mid + 1; else hi = mid; }
    float valid = (f < c[T_ENC - 1]) ? 1.0f : 0.0f;
    int tok = lo < T_ENC ? lo : T_ENC - 1;
    float4 v = ((const float4*)(xe + ((size_t)(b * T_ENC + tok)) * D_))[threadIdx.x];
    v.x *= valid; v.y *= valid; v.z *= valid; v.w *= valid;
    ((float4*)(xd + (size_t)row * D_))[threadIdx.x] = v;
}

// ---------------------------------------------------------------- x += s*proj_w + proj_b (+ dec_pos)
__global__ void addscale_kernel(float* __restrict__ x, const float* __restrict__ sc,
                                const float* __restrict__ pw, const float* __restrict__ pb,
                                const float* __restrict__ pos) {
    int row = blockIdx.x;           // b*ML + t
    int t = row % ML_;
    float s = sc[row];
    float4* xp = (float4*)(x + (size_t)row * D_);
    float4 v = xp[threadIdx.x];
    float4 w4 = ((const float4*)pw)[threadIdx.x];
    float4 b4 = ((const float4*)pb)[threadIdx.x];
    v.x += s * w4.x + b4.x; v.y += s * w4.y + b4.y;
    v.z += s * w4.z + b4.z; v.w += s * w4.w + b4.w;
    if (pos != nullptr) {
        float4 p4 = ((const float4*)(pos + (size_t)t * D_))[threadIdx.x];
        v.x += p4.x; v.y += p4.y; v.z += p4.z; v.w += p4.w;
    }
    xp[threadIdx.x] = v;
}

// ================================================================ host
extern "C" void kernel_launch(void* const* d_in, const int* in_sizes, int n_in,
                              void* d_out, int out_size, void* d_ws, size_t ws_size,
                              hipStream_t stream) {
    (void)in_sizes; (void)n_in; (void)out_size; (void)ws_size;
    const int*   text = (const int*)d_in[0];
    const int*   durt = (const int*)d_in[1];
    const float* lut  = (const float*)d_in[2];
    const float* emb  = (const float*)d_in[3];
    const float* pos  = (const float*)d_in[4];
    const float* dpos = (const float*)d_in[5];
    const int*   e_ai = (const int*)d_in[6];
    const float* e_as = (const float*)d_in[7];
    const int*   e_ui = (const int*)d_in[8];
    const float* e_us = (const float*)d_in[9];
    const int*   e_di = (const int*)d_in[10];
    const float* e_ds = (const float*)d_in[11];
    const float* e_g  = (const float*)d_in[12];
    const float* e_b  = (const float*)d_in[13];
    const int*   d_ai = (const int*)d_in[14];
    const float* d_as = (const float*)d_in[15];
    const int*   d_ui = (const int*)d_in[16];
    const float* d_us = (const float*)d_in[17];
    const int*   d_di = (const int*)d_in[18];
    const float* d_ds = (const float*)d_in[19];
    const float* d_g  = (const float*)d_in[20];
    const float* d_b  = (const float*)d_in[21];
    const float* vp_c1w = (const float*)d_in[22];
    const float* vp_c1b = (const float*)d_in[23];
    const float* vp_g1  = (const float*)d_in[24];
    const float* vp_b1  = (const float*)d_in[25];
    const float* vp_c2w = (const float*)d_in[26];
    const float* vp_c2b = (const float*)d_in[27];
    const float* vp_g2  = (const float*)d_in[28];
    const float* vp_b2  = (const float*)d_in[29];
    const float* vp_lw  = (const float*)d_in[30];
    const float* vp_lb  = (const float*)d_in[31];
    const float* proj_w = (const float*)d_in[32];
    const float* proj_b = (const float*)d_in[33];
    const float* mel_w  = (const float*)d_in[34];
    const float* mel_b  = (const float*)d_in[35];
    const float* pn_w[5] = {(const float*)d_in[36], (const float*)d_in[38], (const float*)d_in[40],
                            (const float*)d_in[42], (const float*)d_in[44]};
    const float* pn_bv[5] = {(const float*)d_in[37], (const float*)d_in[39], (const float*)d_in[41],
                             (const float*)d_in[43], (const float*)d_in[45]};
    const float* pn_g  = (const float*)d_in[46];
    const float* pn_bb = (const float*)d_in[47];

    float* ws = (float*)d_ws;
    float* xe  = ws;                        // [4,512,512]
    float* xd  = ws + 1048576;              // [4,1024,512]
    float* h   = ws + 3145728;              // [4,1024,512]
    float* qb  = ws + 5242880;              // [4,8,1024,64]  (kb, vb follow at QKVSTRIDE_)
    float* kb  = ws + 7340032;
    float* vb  = ws + 9437184;
    float* ob  = ws + 11534336;             // [4,1024,512]
    float* hff = ws + 13631488;             // [4,1024,2048]
    float* vp1 = ws + 22020096;             // [4,1024,256]
    float* vp2 = ws + 23068672;
    int*   cums = (int*)(ws + 24117248);    // [4,512]
    float* pn_a = ws + 24119296;            // [4,512,1024]
    float* pn_b2f = ws + 26216448;

    float* outp   = (float*)d_out;
    float* mel    = outp;                   // [4,1024,80]
    float* melp   = outp + 327680;
    float* durp   = outp + 655360;          // [4,512]
    float* pitch  = outp + 657408;          // [4,1024]
    float* energy = outp + 661504;

    embed_kernel<<<B_ * T_ENC, 128, 0, stream>>>(text, emb, pos, xe);

    auto run_block = [&](float* x, int T, int N, const int* ai, const float* as,
                         const int* ui, const float* us, const int* di, const float* ds,
                         const float* g, const float* bv) {
        ln_kernel<<<N / 4, 256, 0, stream>>>(x, g, bv, h, D_);
        dim3 gq3(N / 128, 24);   // fused q,k,v: M = 1536
        gemm128_kernel<EPI_QKV><<<gq3, 256, 0, stream>>>(h, ai, lut, as, qb, N, 3 * D_, D_, T, 0, QKVSTRIDE_);
        if (T == T_ENC) fattn_kernel<512><<<dim3(512 / 64, B_ * H_), 256, 0, stream>>>(qb, kb, vb, ob);
        else            fattn_kernel<1024><<<dim3(1024 / 64, B_ * H_), 256, 0, stream>>>(qb, kb, vb, ob);
        dim3 go(N / 128, D_ / 64);
        gemm128_kernel<EPI_ADD><<<go, 256, 0, stream>>>(ob, ai + 3 * D_ * D_, lut, as + 3 * D_, x, N, D_, D_, 0, D_, 0);
        ln_kernel<<<N / 4, 256, 0, stream>>>(x, g + D_, bv + D_, h, D_);
        dim3 gu(N / 128, FF_ / 64);
        gemm128_kernel<EPI_GELU><<<gu, 256, 0, stream>>>(h, ui, lut, us, hff, N, FF_, D_, 0, FF_, 0);
        dim3 gd(N / 128, D_ / 64);
        gemm128_kernel<EPI_ADD><<<gd, 256, 0, stream>>>(hff, di, lut, ds, x, N, D_, FF_, 0, D_, 0);
    };

    for (int l = 0; l < L_; l++)
        run_block(xe, T_ENC, B_ * T_ENC,
                  e_ai + (size_t)l * 4 * D_ * D_, e_as + (size_t)l * 4 * D_,
                  e_ui + (size_t)l * FF_ * D_,    e_us + (size_t)l * FF_,
                  e_di + (size_t)l * D_ * FF_,    e_ds + (size_t)l * D_,
                  e_g + (size_t)l * 2 * D_,       e_b + (size_t)l * 2 * D_);

    auto run_varpred = [&](const float* x, int T, int j, float* out) {
        int N = B_ * T;
        dim3 gc1(B_ * (T / 64), FS_ / 64);
        convgemm_kernel<3, 1, 1, CEPI_RELU><<<gc1, 128, 0, stream>>>(
            x, vp_c1w + (size_t)j * FS_ * D_ * 3, vp_c1b + j * FS_, nullptr, nullptr, nullptr,
            vp1, D_, FS_, T);
        ln_kernel<<<N / 4, 256, 0, stream>>>(vp1, vp_g1 + j * FS_, vp_b1 + j * FS_, vp2, FS_);
        convgemm_kernel<3, 1, 1, CEPI_RELU><<<gc1, 128, 0, stream>>>(
            vp2, vp_c2w + (size_t)j * FS_ * FS_ * 3, vp_c2b + j * FS_, nullptr, nullptr, nullptr,
            vp1, FS_, FS_, T);
        ln_kernel<<<N / 4, 256, 0, stream>>>(vp1, vp_g2 + j * FS_, vp_b2 + j * FS_, vp2, FS_);
        vplin_kernel<<<N / 4, 256, 0, stream>>>(vp2, vp_lw + j * FS_, vp_lb + j, out, N);
    };

    run_varpred(xe, T_ENC, 0, durp);

    cumsum_kernel<<<B_, T_ENC, 0, stream>>>(durt, cums);
    regulate_kernel<<<B_ * ML_, 128, 0, stream>>>(xe, cums, xd);

    run_varpred(xd, ML_, 1, pitch);
    addscale_kernel<<<B_ * ML_, 128, 0, stream>>>(xd, pitch, proj_w, proj_b, nullptr);
    run_varpred(xd, ML_, 2, energy);
    addscale_kernel<<<B_ * ML_, 128, 0, stream>>>(xd, energy, proj_w + D_, proj_b + D_, dpos);

    for (int l = 0; l < L_; l++)
        run_block(xd, ML_, B_ * ML_,
                  d_ai + (size_t)l * 4 * D_ * D_, d_as + (size_t)l * 4 * D_,
                  d_ui + (size_t)l * FF_ * D_,    d_us + (size_t)l * FF_,
                  d_di + (size_t)l * D_ * FF_,    d_ds + (size_t)l * D_,
                  d_g + (size_t)l * 2 * D_,       d_b + (size_t)l * 2 * D_);

    {
        dim3 gm((B_ * ML_) / 64, (NMEL_ + 63) / 64);
        gemm_kernel<EPI_BIAS, false><<<gm, 256, 0, stream>>>(xd, mel_w, nullptr, nullptr, mel_b,
                                                             mel, B_ * ML_, NMEL_, D_, 0, NMEL_);
    }

    {
        dim3 g1(B_ * (ML_ / 64), PN_ / 64);
        convgemm_kernel<5, 1, 0, CEPI_TANHBN><<<g1, 128, 0, stream>>>(
            mel, pn_w[0], pn_bv[0], pn_g, pn_bb, nullptr, pn_a, NMEL_, PN_, ML_);
        convgemm_kernel<5, 0, 0, CEPI_TANHBN><<<g1, 128, 0, stream>>>(
            pn_a, pn_w[1], pn_bv[1], pn_g + PN_, pn_bb + PN_, nullptr, pn_b2f, PN_, PN_, ML_);
        convgemm_kernel<5, 0, 0, CEPI_TANHBN><<<g1, 128, 0, stream>>>(
            pn_b2f, pn_w[2], pn_bv[2], pn_g + 2 * PN_, pn_bb + 2 * PN_, nullptr, pn_a, PN_, PN_, ML_);
        convgemm_kernel<5, 0, 0, CEPI_TANHBN><<<g1, 128, 0, stream>>>(
            pn_a, pn_w[3], pn_bv[3], pn_g + 3 * PN_, pn_bb + 3 * PN_, nullptr, pn_b2f, PN_, PN_, ML_);
        dim3 g5(B_ * (ML_ / 64), (NMEL_ + 63) / 64);
        convgemm_kernel<5, 0, 1, CEPI_ADDMEL><<<g5, 128, 0, stream>>>(
            pn_b2f, pn_w[4], pn_bv[4], nullptr, nullptr, mel, melp, PN_, NMEL_, ML_);
    }
}

// Round 6
// 3415.532 us; speedup vs baseline: 1.9591x; 1.9260x over previous
//
#include <hip/hip_runtime.h>
#include <math.h>

#define B_    4
#define T_ENC 512
#define ML_   1024
#define D_    512
#define H_    8
#define HD_   64
#define FF_   2048
#define FS_   256
#define NMEL_ 80
#define PN_   512
#define L_    4
#define QKVSTRIDE_ 2097152

typedef __attribute__((ext_vector_type(8))) short bf16x8;
typedef __attribute__((ext_vector_type(8))) unsigned short u16x8;
typedef __attribute__((ext_vector_type(4))) float f32x4;

__device__ inline unsigned short f2bf(float f) {
    union { float f; unsigned u; } v; v.f = f;
    unsigned r = (v.u + 0x7FFFu + ((v.u >> 16) & 1u)) >> 16;
    return (unsigned short)r;
}

// ---------------------------------------------------------------- embed
__global__ void embed_kernel(const int* __restrict__ text, const float* __restrict__ emb,
                             const float* __restrict__ pos, float* __restrict__ x) {
    int row = blockIdx.x;            // b*T + t
    int t = row % T_ENC;
    int tok = text[row];
    float4 e = ((const float4*)(emb + (size_t)tok * D_))[threadIdx.x];
    float4 p = ((const float4*)(pos + (size_t)t * D_))[threadIdx.x];
    e.x += p.x; e.y += p.y; e.z += p.z; e.w += p.w;
    ((float4*)(x + (size_t)row * D_))[threadIdx.x] = e;
}

// ---------------------------------------------------------------- layernorm: wave per row, shuffle reduce
__global__ __launch_bounds__(256)
void ln_kernel(const float* __restrict__ x, const float* __restrict__ g,
               const float* __restrict__ b, float* __restrict__ out, int D) {
    int row = blockIdx.x * 4 + (threadIdx.x >> 6);
    int lane = threadIdx.x & 63;
    const float* xr = x + (size_t)row * D;
    float4 vals[2];
    int nit = D >> 8;                // D=512 -> 2, D=256 -> 1
    float s = 0.f, q = 0.f;
#pragma unroll 2
    for (int it = 0; it < nit; it++) {
        float4 v = ((const float4*)xr)[lane + it * 64];
        vals[it] = v;
        s += v.x + v.y + v.z + v.w;
        q += v.x * v.x + v.y * v.y + v.z * v.z + v.w * v.w;
    }
#pragma unroll
    for (int off = 32; off; off >>= 1) {
        s += __shfl_xor(s, off);
        q += __shfl_xor(q, off);
    }
    float mean = s / D;
    float var  = q / D - mean * mean;
    float rstd = rsqrtf(var + 1e-5f);
    float* orow = out + (size_t)row * D;
#pragma unroll 2
    for (int it = 0; it < nit; it++) {
        int d4 = lane + it * 64;
        float4 gv = ((const float4*)g)[d4];
        float4 bv = ((const float4*)b)[d4];
        float4 v = vals[it];
        v.x = (v.x - mean) * rstd * gv.x + bv.x;
        v.y = (v.y - mean) * rstd * gv.y + bv.y;
        v.z = (v.z - mean) * rstd * gv.z + bv.z;
        v.w = (v.w - mean) * rstd * gv.w + bv.w;
        ((float4*)orow)[d4] = v;
    }
}

// ---------------------------------------------------------------- small fp32 GEMM (mel proj only)
enum { EPI_STORE = 0, EPI_ADD = 1, EPI_GELU = 2, EPI_QKV = 3, EPI_BIAS = 4 };

template<int EPI, bool QUANT>
__global__ __launch_bounds__(256)
void gemm_kernel(const float* __restrict__ X, const void* __restrict__ Wv,
                 const float* __restrict__ lut, const float* __restrict__ scale,
                 const float* __restrict__ bias, float* __restrict__ out,
                 int N, int M, int K, int Ttok, int ldo) {
    __shared__ float Xs[16][68];
    __shared__ float Ws[16][68];
    int tid = threadIdx.x;
    int n0 = blockIdx.x * 64, m0 = blockIdx.y * 64;
    int tx = tid & 15, ty = tid >> 4;
    int nl = tid >> 2, kq = (tid & 3) * 4;
    const float* Xp = X + (size_t)(n0 + nl) * K + kq;
    const float* Wf = (const float*)Wv;
    size_t wrow = (size_t)(m0 + nl) * K + kq;
    bool wok = (m0 + nl) < M;
    float c[4][4] = {{0.f}};
    for (int k0 = 0; k0 < K; k0 += 16) {
        __syncthreads();
        float4 xv = *(const float4*)(Xp + k0);
        float w0, w1, w2, w3;
        if (wok) {
            float4 w4 = *(const float4*)(Wf + wrow + k0);
            w0 = w4.x; w1 = w4.y; w2 = w4.z; w3 = w4.w;
        } else { w0 = w1 = w2 = w3 = 0.f; }
        Xs[kq + 0][nl] = xv.x; Xs[kq + 1][nl] = xv.y; Xs[kq + 2][nl] = xv.z; Xs[kq + 3][nl] = xv.w;
        Ws[kq + 0][nl] = w0;   Ws[kq + 1][nl] = w1;   Ws[kq + 2][nl] = w2;   Ws[kq + 3][nl] = w3;
        __syncthreads();
#pragma unroll
        for (int kk = 0; kk < 16; kk++) {
            float4 a = *(const float4*)&Xs[kk][ty * 4];
            float4 w = *(const float4*)&Ws[kk][tx * 4];
            c[0][0] = fmaf(a.x, w.x, c[0][0]); c[0][1] = fmaf(a.x, w.y, c[0][1]);
            c[0][2] = fmaf(a.x, w.z, c[0][2]); c[0][3] = fmaf(a.x, w.w, c[0][3]);
            c[1][0] = fmaf(a.y, w.x, c[1][0]); c[1][1] = fmaf(a.y, w.y, c[1][1]);
            c[1][2] = fmaf(a.y, w.z, c[1][2]); c[1][3] = fmaf(a.y, w.w, c[1][3]);
            c[2][0] = fmaf(a.z, w.x, c[2][0]); c[2][1] = fmaf(a.z, w.y, c[2][1]);
            c[2][2] = fmaf(a.z, w.z, c[2][2]); c[2][3] = fmaf(a.z, w.w, c[2][3]);
            c[3][0] = fmaf(a.w, w.x, c[3][0]); c[3][1] = fmaf(a.w, w.y, c[3][1]);
            c[3][2] = fmaf(a.w, w.z, c[3][2]); c[3][3] = fmaf(a.w, w.w, c[3][3]);
        }
    }
#pragma unroll
    for (int i = 0; i < 4; i++) {
        int n = n0 + ty * 4 + i;
#pragma unroll
        for (int j = 0; j < 4; j++) {
            int m = m0 + tx * 4 + j;
            float v = c[i][j];
            if (EPI == EPI_BIAS) {
                if (m < M) out[(size_t)n * ldo + m] = v + bias[m];
            } else if (EPI == EPI_STORE) {
                if (m < M) out[(size_t)n * ldo + m] = v;
            }
        }
    }
}

// ---------------------------------------------------------------- bf16 MFMA quant GEMM
// Y[N,M] = X[N,K] @ (dequant W)^T ; dequant w = (lut0 + idx*step) * scale[m] (affine LUT).
// tile 128(N) x 64(M), 256 thr = 4 waves (2x2 of 64n x 32m), BK=32, dbuf LDS, fp32 acc.
template<int EPI>
__global__ __launch_bounds__(256)
void bgemm_kernel(const float* __restrict__ X, const int* __restrict__ Wi,
                  const float* __restrict__ lut, const float* __restrict__ scale,
                  float* __restrict__ out, int N, int M, int K, int Ttok, int ldo,
                  int qkv_stride) {
    __shared__ unsigned short As[2][128][40];   // [n][k], 80B row stride (16B-mult)
    __shared__ unsigned short Bs[2][64][40];    // [m][k]
    int tid = threadIdx.x;
    int n0 = blockIdx.x * 128, m0 = blockIdx.y * 64;
    float lo = lut[0];
    float step = lut[1] - lut[0];
    // staging coords
    int arow = tid >> 1, akh = (tid & 1) * 16;
    int brow = tid >> 2, bkq = (tid & 3) * 8;
    const float* Xp = X + (size_t)(n0 + arow) * K + akh;
    const int*   Wp = Wi + (size_t)(m0 + brow) * K + bkq;
    // wave/lane
    int lane = tid & 63, wid = tid >> 6;
    int lr = lane & 15, lk = lane >> 4;
    int wr = wid >> 1, wc = wid & 1;       // n-off 64*wr, m-off 32*wc

    f32x4 acc[4][2];
#pragma unroll
    for (int i = 0; i < 4; i++)
#pragma unroll
        for (int j = 0; j < 2; j++) { f32x4 z = {0.f, 0.f, 0.f, 0.f}; acc[i][j] = z; }

    float4 a0, a1, a2, a3;
    int4 i0, i1;
    auto loadr = [&](int kb) {
        const float4* xp = (const float4*)(Xp + kb);
        a0 = xp[0]; a1 = xp[1]; a2 = xp[2]; a3 = xp[3];
        const int4* ip = (const int4*)(Wp + kb);
        i0 = ip[0]; i1 = ip[1];
    };
    auto storer = [&](int buf) {
        u16x8 w0, w1;
        w0[0] = f2bf(a0.x); w0[1] = f2bf(a0.y); w0[2] = f2bf(a0.z); w0[3] = f2bf(a0.w);
        w0[4] = f2bf(a1.x); w0[5] = f2bf(a1.y); w0[6] = f2bf(a1.z); w0[7] = f2bf(a1.w);
        w1[0] = f2bf(a2.x); w1[1] = f2bf(a2.y); w1[2] = f2bf(a2.z); w1[3] = f2bf(a2.w);
        w1[4] = f2bf(a3.x); w1[5] = f2bf(a3.y); w1[6] = f2bf(a3.z); w1[7] = f2bf(a3.w);
        *(u16x8*)&As[buf][arow][akh]     = w0;
        *(u16x8*)&As[buf][arow][akh + 8] = w1;
        u16x8 wb;
        wb[0] = f2bf(fmaf((float)i0.x, step, lo)); wb[1] = f2bf(fmaf((float)i0.y, step, lo));
        wb[2] = f2bf(fmaf((float)i0.z, step, lo)); wb[3] = f2bf(fmaf((float)i0.w, step, lo));
        wb[4] = f2bf(fmaf((float)i1.x, step, lo)); wb[5] = f2bf(fmaf((float)i1.y, step, lo));
        wb[6] = f2bf(fmaf((float)i1.z, step, lo)); wb[7] = f2bf(fmaf((float)i1.w, step, lo));
        *(u16x8*)&Bs[buf][brow][bkq] = wb;
    };
    auto compute = [&](int buf) {
        bf16x8 af[4], bfv[2];
#pragma unroll
        for (int i = 0; i < 4; i++)
            af[i] = *(const bf16x8*)&As[buf][64 * wr + 16 * i + lr][lk * 8];
#pragma unroll
        for (int j = 0; j < 2; j++)
            bfv[j] = *(const bf16x8*)&Bs[buf][32 * wc + 16 * j + lr][lk * 8];
#pragma unroll
        for (int i = 0; i < 4; i++)
#pragma unroll
            for (int j = 0; j < 2; j++)
                acc[i][j] = __builtin_amdgcn_mfma_f32_16x16x32_bf16(af[i], bfv[j], acc[i][j], 0, 0, 0);
    };

    loadr(0);
    storer(0);
    int nc = K >> 5;
    for (int c = 0; c < nc; c++) {
        int cur = c & 1;
        __syncthreads();
        bool more = (c + 1 < nc);
        if (more) loadr((c + 1) << 5);
        compute(cur);
        if (more) storer(cur ^ 1);
    }

    // epilogue (fp32): apply scale[m], then EPI
    float sc[2];
#pragma unroll
    for (int j = 0; j < 2; j++) sc[j] = scale[m0 + 32 * wc + 16 * j + lr];
#pragma unroll
    for (int i = 0; i < 4; i++) {
#pragma unroll
        for (int j = 0; j < 2; j++) {
            int m = m0 + 32 * wc + 16 * j + lr;
#pragma unroll
            for (int r = 0; r < 4; r++) {
                int n = n0 + 64 * wr + 16 * i + lk * 4 + r;
                float v = acc[i][j][r] * sc[j];
                if (EPI == EPI_STORE) {
                    out[(size_t)n * ldo + m] = v;
                } else if (EPI == EPI_ADD) {
                    out[(size_t)n * ldo + m] += v;
                } else if (EPI == EPI_GELU) {
                    out[(size_t)n * ldo + m] = 0.5f * v * (1.0f + erff(v * 0.70710678118654752f));
                } else if (EPI == EPI_QKV) {
                    int mat = m >> 9, h = (m >> 6) & 7, dd = m & 63;
                    int b = n / Ttok, t = n - b * Ttok;
                    out[(size_t)mat * qkv_stride + ((size_t)(b * H_ + h) * Ttok + t) * HD_ + dd] = v;
                }
            }
        }
    }
}

// ---------------------------------------------------------------- flash attention (fp32, LDS-tiled)
template<int TLEN>
__global__ __launch_bounds__(256)
void fattn_kernel(const float* __restrict__ q, const float* __restrict__ k,
                  const float* __restrict__ v, float* __restrict__ o_out) {
    __shared__ float Qs[64][68];
    __shared__ float KP[64][64];
    __shared__ float Vs[64][64];
    int tid = threadIdx.x;
    int tx = tid & 15, ty = tid >> 4;
    int bh = blockIdx.y;
    int q0 = blockIdx.x * 64;
    const float* Qb = q + ((size_t)bh * TLEN + q0) * HD_;
    const float* Kb = k + (size_t)bh * TLEN * HD_;
    const float* Vb = v + (size_t)bh * TLEN * HD_;
    {
        int r = tid >> 4, f = tid & 15;
#pragma unroll
        for (int it = 0; it < 4; it++) {
            int rr = r + 16 * it;
            float4 t4 = *(const float4*)(Qb + (size_t)rr * HD_ + f * 4);
            *(float4*)&Qs[rr][f * 4] = t4;
        }
    }
    float o[4][4] = {{0.f}};
    float m[4], l[4];
#pragma unroll
    for (int i = 0; i < 4; i++) { m[i] = -3e38f; l[i] = 0.f; }
    __syncthreads();

    for (int c0 = 0; c0 < TLEN; c0 += 64) {
        {
            int c = tid >> 2, fo = tid & 3;
#pragma unroll
            for (int it = 0; it < 4; it++) {
                int f = fo + 4 * it;
                float4 t4 = *(const float4*)(Kb + (size_t)(c0 + c) * HD_ + f * 4);
                KP[f * 4 + 0][c] = t4.x; KP[f * 4 + 1][c] = t4.y;
                KP[f * 4 + 2][c] = t4.z; KP[f * 4 + 3][c] = t4.w;
            }
            int r = tid >> 4, ff = tid & 15;
#pragma unroll
            for (int it = 0; it < 4; it++) {
                int rr = r + 16 * it;
                float4 t4 = *(const float4*)(Vb + (size_t)(c0 + rr) * HD_ + ff * 4);
                *(float4*)&Vs[rr][ff * 4] = t4;
            }
        }
        __syncthreads();
        float s[4][4] = {{0.f}};
        for (int k0 = 0; k0 < 64; k0 += 4) {
            float4 qa[4], kb4[4];
#pragma unroll
            for (int i = 0; i < 4; i++) qa[i] = *(const float4*)&Qs[ty * 4 + i][k0];
#pragma unroll
            for (int kk = 0; kk < 4; kk++) kb4[kk] = *(const float4*)&KP[k0 + kk][tx * 4];
#pragma unroll
            for (int i = 0; i < 4; i++) {
                const float* qf = (const float*)&qa[i];
#pragma unroll
                for (int kk = 0; kk < 4; kk++) {
                    float a = qf[kk];
                    s[i][0] = fmaf(a, kb4[kk].x, s[i][0]);
                    s[i][1] = fmaf(a, kb4[kk].y, s[i][1]);
                    s[i][2] = fmaf(a, kb4[kk].z, s[i][2]);
                    s[i][3] = fmaf(a, kb4[kk].w, s[i][3]);
                }
            }
        }
        __syncthreads();
#pragma unroll
        for (int i = 0; i < 4; i++) {
#pragma unroll
            for (int j = 0; j < 4; j++) s[i][j] *= 0.125f;
            float mx = fmaxf(fmaxf(s[i][0], s[i][1]), fmaxf(s[i][2], s[i][3]));
            mx = fmaxf(mx, __shfl_xor(mx, 1));
            mx = fmaxf(mx, __shfl_xor(mx, 2));
            mx = fmaxf(mx, __shfl_xor(mx, 4));
            mx = fmaxf(mx, __shfl_xor(mx, 8));
            float mn = fmaxf(m[i], mx);
            float f = __expf(m[i] - mn);
            float ps = 0.f;
#pragma unroll
            for (int j = 0; j < 4; j++) { float p = __expf(s[i][j] - mn); s[i][j] = p; ps += p; }
            ps += __shfl_xor(ps, 1);
            ps += __shfl_xor(ps, 2);
            ps += __shfl_xor(ps, 4);
            ps += __shfl_xor(ps, 8);
            l[i] = l[i] * f + ps;
            m[i] = mn;
#pragma unroll
            for (int j = 0; j < 4; j++) o[i][j] *= f;
            *(float4*)&KP[ty * 4 + i][tx * 4] = *(float4*)&s[i][0];
        }
        __syncthreads();
        for (int cc0 = 0; cc0 < 64; cc0 += 4) {
            float4 pa[4], vb4[4];
#pragma unroll
            for (int i = 0; i < 4; i++) pa[i] = *(const float4*)&KP[ty * 4 + i][cc0];
#pragma unroll
            for (int cc = 0; cc < 4; cc++) vb4[cc] = *(const float4*)&Vs[cc0 + cc][tx * 4];
#pragma unroll
            for (int i = 0; i < 4; i++) {
                const float* pf = (const float*)&pa[i];
#pragma unroll
                for (int cc = 0; cc < 4; cc++) {
                    float p = pf[cc];
                    o[i][0] = fmaf(p, vb4[cc].x, o[i][0]);
                    o[i][1] = fmaf(p, vb4[cc].y, o[i][1]);
                    o[i][2] = fmaf(p, vb4[cc].z, o[i][2]);
                    o[i][3] = fmaf(p, vb4[cc].w, o[i][3]);
                }
            }
        }
        __syncthreads();
    }
    int b = bh >> 3, hh = bh & 7;
#pragma unroll
    for (int i = 0; i < 4; i++) {
        float inv = 1.0f / l[i];
        int row = q0 + ty * 4 + i;
        float4 r4;
        r4.x = o[i][0] * inv; r4.y = o[i][1] * inv;
        r4.z = o[i][2] * inv; r4.w = o[i][3] * inv;
        *(float4*)(o_out + ((size_t)(b * TLEN + row)) * D_ + hh * HD_ + tx * 4) = r4;
    }
}

// ---------------------------------------------------------------- conv1d as tiled GEMM (R3 shape) + split-Cin
// 256 threads; tile 64t x 64oc; 4x4 micro. SPLIT>1: grid.z splits Cin, raw partials out.
enum { CEPI_NONE = 0, CEPI_RELU = 1, CEPI_TANHBN = 2, CEPI_ADDMEL = 3 };

template<int KW, int IN_TM, int OUT_TM, int EPI, int SPLIT>
__global__ __launch_bounds__(256)
void convgemm_kernel(const float* __restrict__ in, const float* __restrict__ w,
                     const float* __restrict__ bias, const float* __restrict__ bng,
                     const float* __restrict__ bnb, const float* __restrict__ meladd,
                     float* __restrict__ out, int Cin, int Cout, int T, int pstride) {
    constexpr int PAD = KW / 2;
    __shared__ float Xs[16][72];
    __shared__ float Ws[16 * KW][68];
    int tid = threadIdx.x;
    int tx = tid & 15, ty = tid >> 4;
    int ntile = T >> 6;
    int b = blockIdx.x / ntile, tc = blockIdx.x % ntile;
    int t0 = tc * 64;
    int m0 = blockIdx.y * 64;
    int z = (SPLIT > 1) ? blockIdx.z : 0;
    int cstart = z * (Cin / SPLIT), cend = cstart + Cin / SPLIT;
    constexpr int XW = 64 + 2 * PAD;
    constexpr int F4PO = (16 * KW) / 4;
    int o_l = tid >> 2, part = tid & 3;
    bool o_ok = (m0 + o_l) < Cout;

    float acc[4][4];
#pragma unroll
    for (int i = 0; i < 4; i++)
#pragma unroll
        for (int j = 0; j < 4; j++) acc[i][j] = 0.f;

    for (int ci0 = cstart; ci0 < cend; ci0 += 16) {
        __syncthreads();
        {
            const float* wb = w + ((size_t)(m0 + o_l) * Cin + ci0) * KW;
            for (int qq = part; qq < F4PO; qq += 4) {
                float4 t4 = o_ok ? *(const float4*)(wb + qq * 4)
                                 : make_float4(0.f, 0.f, 0.f, 0.f);
                Ws[qq * 4 + 0][o_l] = t4.x; Ws[qq * 4 + 1][o_l] = t4.y;
                Ws[qq * 4 + 2][o_l] = t4.z; Ws[qq * 4 + 3][o_l] = t4.w;
            }
        }
        for (int idx = tid; idx < 16 * XW; idx += 256) {
            int r = idx / XW, ccol = idx - r * XW;
            int t = t0 + ccol - PAD;
            float xv = 0.f;
            if (t >= 0 && t < T)
                xv = (IN_TM == 0) ? in[((size_t)(b * Cin + ci0 + r)) * T + t]
                                  : in[((size_t)(b * T + t)) * Cin + ci0 + r];
            Xs[r][ccol] = xv;
        }
        __syncthreads();
#pragma unroll
        for (int kk = 0; kk < 16; kk++) {
            float xr[8];
            float4 xa = *(const float4*)&Xs[kk][tx * 4];
            float4 xb = *(const float4*)&Xs[kk][tx * 4 + 4];
            xr[0] = xa.x; xr[1] = xa.y; xr[2] = xa.z; xr[3] = xa.w;
            xr[4] = xb.x; xr[5] = xb.y; xr[6] = xb.z; xr[7] = xb.w;
#pragma unroll
            for (int k = 0; k < KW; k++) {
                float4 w4 = *(const float4*)&Ws[kk * KW + k][ty * 4];
                const float* wf = (const float*)&w4;
#pragma unroll
                for (int i = 0; i < 4; i++) {
                    float wv = wf[i];
#pragma unroll
                    for (int j = 0; j < 4; j++)
                        acc[i][j] = fmaf(wv, xr[j + k], acc[i][j]);
                }
            }
        }
    }
    const float inv = 0.99999500003749969f;   // 1/sqrt(1+1e-5)
#pragma unroll
    for (int i = 0; i < 4; i++) {
        int o = m0 + ty * 4 + i;
        if (o >= Cout) continue;
        if (SPLIT > 1) {
            // raw partials, epilogue deferred to combine
            float* po = out + (size_t)z * pstride;
            if (OUT_TM == 0) {
                float4 v4 = make_float4(acc[i][0], acc[i][1], acc[i][2], acc[i][3]);
                *(float4*)(po + ((size_t)(b * Cout + o)) * T + t0 + tx * 4) = v4;
            } else {
#pragma unroll
                for (int j = 0; j < 4; j++)
                    po[((size_t)(b * T + t0 + tx * 4 + j)) * Cout + o] = acc[i][j];
            }
        } else {
            float bsv = bias[o];
            float g = 0.f, bb = 0.f;
            if (EPI == CEPI_TANHBN) { g = bng[o]; bb = bnb[o]; }
            float vj[4];
#pragma unroll
            for (int j = 0; j < 4; j++) {
                int t = t0 + tx * 4 + j;
                float v = acc[i][j] + bsv;
                if (EPI == CEPI_RELU) {
                    v = fmaxf(v, 0.f);
                } else if (EPI == CEPI_TANHBN) {
                    float zz = v * inv * g + bb;
                    zz = fminf(fmaxf(zz, -15.f), 15.f);
                    float e2 = __expf(2.f * zz);
                    v = (e2 - 1.f) / (e2 + 1.f);
                } else if (EPI == CEPI_ADDMEL) {
                    v += meladd[((size_t)(b * T + t)) * NMEL_ + o];
                }
                vj[j] = v;
            }
            if (OUT_TM == 0) {
                *(float4*)(out + ((size_t)(b * Cout + o)) * T + t0 + tx * 4) =
                    make_float4(vj[0], vj[1], vj[2], vj[3]);
            } else {
#pragma unroll
                for (int j = 0; j < 4; j++)
                    out[((size_t)(b * T + t0 + tx * 4 + j)) * Cout + o] = vj[j];
            }
        }
    }
}

// ---------------------------------------------------------------- combine 2 conv partials + bias + activation
template<int OUT_TM, int EPI>
__global__ __launch_bounds__(256)
void convcomb_kernel(const float* __restrict__ p, int pstride, const float* __restrict__ bias,
                     const float* __restrict__ bng, const float* __restrict__ bnb,
                     const float* __restrict__ meladd, float* __restrict__ out,
                     int Cout, int T, int total) {
    int idx = blockIdx.x * 256 + threadIdx.x;
    if (idx >= total) return;
    float v = p[idx] + p[idx + pstride];
    int o = (OUT_TM == 0) ? (idx / T) % Cout : idx % Cout;
    v += bias[o];
    if (EPI == CEPI_RELU) {
        v = fmaxf(v, 0.f);
    } else if (EPI == CEPI_TANHBN) {
        const float inv = 0.99999500003749969f;
        float zz = v * inv * bng[o] + bnb[o];
        zz = fminf(fmaxf(zz, -15.f), 15.f);
        float e2 = __expf(2.f * zz);
        v = (e2 - 1.f) / (e2 + 1.f);
    } else if (EPI == CEPI_ADDMEL) {
        v += meladd[idx];   // OUT_TM=1, Cout==NMEL: identical flat layout
    }
    out[idx] = v;
}

// ---------------------------------------------------------------- variance-predictor linear (FS -> 1)
__global__ void vplin_kernel(const float* __restrict__ h, const float* __restrict__ lw,
                             const float* __restrict__ lb, float* __restrict__ out, int ntok) {
    int row = blockIdx.x * 4 + (threadIdx.x >> 6);
    int lane = threadIdx.x & 63;
    if (row >= ntok) return;
    const float* hr = h + (size_t)row * FS_;
    float s = 0.f;
    for (int c = lane; c < FS_; c += 64) s += hr[c] * lw[c];
#pragma unroll
    for (int off = 32; off; off >>= 1) s += __shfl_down(s, off);
    if (lane == 0) out[row] = s + lb[0];
}

// ---------------------------------------------------------------- cumsum of durations (per batch)
__global__ void cumsum_kernel(const int* __restrict__ dur, int* __restrict__ cums) {
    __shared__ int c[T_ENC];
    int b = blockIdx.x, tid = threadIdx.x;
    c[tid] = dur[b * T_ENC + tid];
    __syncthreads();
    for (int off = 1; off < T_ENC; off <<= 1) {
        int v = (tid >= off) ? c[tid - off] : 0;
        __syncthreads();
        c[tid] += v;
        __syncthreads();
    }
    cums[b * T_ENC + tid] = c[tid];
}

// ---------------------------------------------------------------- length regulator
__global__ void regulate_kernel(const float* __restrict__ xe, const int* __restrict__ cums,
                                float* __restrict__ xd) {
    int row = blockIdx.x;           // b*ML + f
    int b = row / ML_, f = row % ML_;
    const int* c = cums + b * T_ENC;
    int lo = 0, hi = T_ENC;
    while (lo < hi) { int mid = (lo + hi) >> 1; if (c[mid] <= f) lo = mid + 1; else hi = mid; }
    float valid = (f < c[T_ENC - 1]) ? 1.0f : 0.0f;
    int tok = lo < T_ENC ? lo : T_ENC - 1;
    float4 v = ((const float4*)(xe + ((size_t)(b * T_ENC + tok)) * D_))[threadIdx.x];
    v.x *= valid; v.y *= valid; v.z *= valid; v.w *= valid;
    ((float4*)(xd + (size_t)row * D_))[threadIdx.x] = v;
}

// ---------------------------------------------------------------- x += s*proj_w + proj_b (+ dec_pos)
__global__ void addscale_kernel(float* __restrict__ x, const float* __restrict__ sc,
                                const float* __restrict__ pw, const float* __restrict__ pb,
                                const float* __restrict__ pos) {
    int row = blockIdx.x;           // b*ML + t
    int t = row % ML_;
    float s = sc[row];
    float4* xp = (float4*)(x + (size_t)row * D_);
    float4 v = xp[threadIdx.x];
    float4 w4 = ((const float4*)pw)[threadIdx.x];
    float4 b4 = ((const float4*)pb)[threadIdx.x];
    v.x += s * w4.x + b4.x; v.y += s * w4.y + b4.y;
    v.z += s * w4.z + b4.z; v.w += s * w4.w + b4.w;
    if (pos != nullptr) {
        float4 p4 = ((const float4*)(pos + (size_t)t * D_))[threadIdx.x];
        v.x += p4.x; v.y += p4.y; v.z += p4.z; v.w += p4.w;
    }
    xp[threadIdx.x] = v;
}

// ================================================================ host
extern "C" void kernel_launch(void* const* d_in, const int* in_sizes, int n_in,
                              void* d_out, int out_size, void* d_ws, size_t ws_size,
                              hipStream_t stream) {
    (void)in_sizes; (void)n_in; (void)out_size; (void)ws_size;
    const int*   text = (const int*)d_in[0];
    const int*   durt = (const int*)d_in[1];
    const float* lut  = (const float*)d_in[2];
    const float* emb  = (const float*)d_in[3];
    const float* pos  = (const float*)d_in[4];
    const float* dpos = (const float*)d_in[5];
    const int*   e_ai = (const int*)d_in[6];
    const float* e_as = (const float*)d_in[7];
    const int*   e_ui = (const int*)d_in[8];
    const float* e_us = (const float*)d_in[9];
    const int*   e_di = (const int*)d_in[10];
    const float* e_ds = (const float*)d_in[11];
    const float* e_g  = (const float*)d_in[12];
    const float* e_b  = (const float*)d_in[13];
    const int*   d_ai = (const int*)d_in[14];
    const float* d_as = (const float*)d_in[15];
    const int*   d_ui = (const int*)d_in[16];
    const float* d_us = (const float*)d_in[17];
    const int*   d_di = (const int*)d_in[18];
    const float* d_ds = (const float*)d_in[19];
    const float* d_g  = (const float*)d_in[20];
    const float* d_b  = (const float*)d_in[21];
    const float* vp_c1w = (const float*)d_in[22];
    const float* vp_c1b = (const float*)d_in[23];
    const float* vp_g1  = (const float*)d_in[24];
    const float* vp_b1  = (const float*)d_in[25];
    const float* vp_c2w = (const float*)d_in[26];
    const float* vp_c2b = (const float*)d_in[27];
    const float* vp_g2  = (const float*)d_in[28];
    const float* vp_b2  = (const float*)d_in[29];
    const float* vp_lw  = (const float*)d_in[30];
    const float* vp_lb  = (const float*)d_in[31];
    const float* proj_w = (const float*)d_in[32];
    const float* proj_b = (const float*)d_in[33];
    const float* mel_w  = (const float*)d_in[34];
    const float* mel_b  = (const float*)d_in[35];
    const float* pn_w[5] = {(const float*)d_in[36], (const float*)d_in[38], (const float*)d_in[40],
                            (const float*)d_in[42], (const float*)d_in[44]};
    const float* pn_bv[5] = {(const float*)d_in[37], (const float*)d_in[39], (const float*)d_in[41],
                             (const float*)d_in[43], (const float*)d_in[45]};
    const float* pn_g  = (const float*)d_in[46];
    const float* pn_bb = (const float*)d_in[47];

    float* ws = (float*)d_ws;
    float* xe  = ws;                        // [4,512,512]
    float* xd  = ws + 1048576;              // [4,1024,512]
    float* h   = ws + 3145728;              // [4,1024,512]
    float* qb  = ws + 5242880;              // [4,8,1024,64]  (kb, vb follow at QKVSTRIDE_)
    float* kb  = ws + 7340032;
    float* vb  = ws + 9437184;
    float* ob  = ws + 11534336;             // [4,1024,512]
    float* hff = ws + 13631488;             // [4,1024,2048] — also conv partial scratch
    float* vp1 = ws + 22020096;             // [4,1024,256]
    float* vp2 = ws + 23068672;
    int*   cums = (int*)(ws + 24117248);    // [4,512]
    float* pn_a = ws + 24119296;            // [4,512,1024]
    float* pn_b2f = ws + 26216448;

    float* outp   = (float*)d_out;
    float* mel    = outp;                   // [4,1024,80]
    float* melp   = outp + 327680;
    float* durp   = outp + 655360;          // [4,512]
    float* pitch  = outp + 657408;          // [4,1024]
    float* energy = outp + 661504;

    embed_kernel<<<B_ * T_ENC, 128, 0, stream>>>(text, emb, pos, xe);

    auto run_block = [&](float* x, int T, int N, const int* ai, const float* as,
                         const int* ui, const float* us, const int* di, const float* ds,
                         const float* g, const float* bv) {
        ln_kernel<<<N / 4, 256, 0, stream>>>(x, g, bv, h, D_);
        dim3 gq3(N / 128, 24);   // fused q,k,v: M = 1536
        bgemm_kernel<EPI_QKV><<<gq3, 256, 0, stream>>>(h, ai, lut, as, qb, N, 3 * D_, D_, T, 0, QKVSTRIDE_);
        if (T == T_ENC) fattn_kernel<512><<<dim3(512 / 64, B_ * H_), 256, 0, stream>>>(qb, kb, vb, ob);
        else            fattn_kernel<1024><<<dim3(1024 / 64, B_ * H_), 256, 0, stream>>>(qb, kb, vb, ob);
        dim3 go(N / 128, D_ / 64);
        bgemm_kernel<EPI_ADD><<<go, 256, 0, stream>>>(ob, ai + 3 * D_ * D_, lut, as + 3 * D_, x, N, D_, D_, 0, D_, 0);
        ln_kernel<<<N / 4, 256, 0, stream>>>(x, g + D_, bv + D_, h, D_);
        dim3 gu(N / 128, FF_ / 64);
        bgemm_kernel<EPI_GELU><<<gu, 256, 0, stream>>>(h, ui, lut, us, hff, N, FF_, D_, 0, FF_, 0);
        dim3 gd(N / 128, D_ / 64);
        bgemm_kernel<EPI_ADD><<<gd, 256, 0, stream>>>(hff, di, lut, ds, x, N, D_, FF_, 0, D_, 0);
    };

    for (int l = 0; l < L_; l++)
        run_block(xe, T_ENC, B_ * T_ENC,
                  e_ai + (size_t)l * 4 * D_ * D_, e_as + (size_t)l * 4 * D_,
                  e_ui + (size_t)l * FF_ * D_,    e_us + (size_t)l * FF_,
                  e_di + (size_t)l * D_ * FF_,    e_ds + (size_t)l * D_,
                  e_g + (size_t)l * 2 * D_,       e_b + (size_t)l * 2 * D_);

    // variance predictor: split-Cin x2 convs, partials in hff
    auto run_varpred = [&](const float* x, int T, int j, float* out) {
        int N = B_ * T;
        int ps1 = B_ * FS_ * T;          // partial stride
        dim3 gc1(B_ * (T / 64), FS_ / 64, 2);
        convgemm_kernel<3, 1, 1, CEPI_NONE, 2><<<gc1, 256, 0, stream>>>(
            x, vp_c1w + (size_t)j * FS_ * D_ * 3, nullptr, nullptr, nullptr, nullptr,
            hff, D_, FS_, T, ps1);
        convcomb_kernel<1, CEPI_RELU><<<(ps1 + 255) / 256, 256, 0, stream>>>(
            hff, ps1, vp_c1b + j * FS_, nullptr, nullptr, nullptr, vp1, FS_, T, ps1);
        ln_kernel<<<N / 4, 256, 0, stream>>>(vp1, vp_g1 + j * FS_, vp_b1 + j * FS_, vp2, FS_);
        convgemm_kernel<3, 1, 1, CEPI_NONE, 2><<<gc1, 256, 0, stream>>>(
            vp2, vp_c2w + (size_t)j * FS_ * FS_ * 3, nullptr, nullptr, nullptr, nullptr,
            hff, FS_, FS_, T, ps1);
        convcomb_kernel<1, CEPI_RELU><<<(ps1 + 255) / 256, 256, 0, stream>>>(
            hff, ps1, vp_c2b + j * FS_, nullptr, nullptr, nullptr, vp1, FS_, T, ps1);
        ln_kernel<<<N / 4, 256, 0, stream>>>(vp1, vp_g2 + j * FS_, vp_b2 + j * FS_, vp2, FS_);
        vplin_kernel<<<N / 4, 256, 0, stream>>>(vp2, vp_lw + j * FS_, vp_lb + j, out, N);
    };

    run_varpred(xe, T_ENC, 0, durp);

    cumsum_kernel<<<B_, T_ENC, 0, stream>>>(durt, cums);
    regulate_kernel<<<B_ * ML_, 128, 0, stream>>>(xe, cums, xd);

    run_varpred(xd, ML_, 1, pitch);
    addscale_kernel<<<B_ * ML_, 128, 0, stream>>>(xd, pitch, proj_w, proj_b, nullptr);
    run_varpred(xd, ML_, 2, energy);
    addscale_kernel<<<B_ * ML_, 128, 0, stream>>>(xd, energy, proj_w + D_, proj_b + D_, dpos);

    for (int l = 0; l < L_; l++)
        run_block(xd, ML_, B_ * ML_,
                  d_ai + (size_t)l * 4 * D_ * D_, d_as + (size_t)l * 4 * D_,
                  d_ui + (size_t)l * FF_ * D_,    d_us + (size_t)l * FF_,
                  d_di + (size_t)l * D_ * FF_,    d_ds + (size_t)l * D_,
                  d_g + (size_t)l * 2 * D_,       d_b + (size_t)l * 2 * D_);

    {
        dim3 gm((B_ * ML_) / 64, (NMEL_ + 63) / 64);
        gemm_kernel<EPI_BIAS, false><<<gm, 256, 0, stream>>>(xd, mel_w, nullptr, nullptr, mel_b,
                                                             mel, B_ * ML_, NMEL_, D_, 0, NMEL_);
    }

    // postnet: layer1 (Cin=80) unsplit; layers 2-5 split-Cin x2
    {
        int psm = B_ * PN_ * ML_;        // 2,097,152
        int ps5 = B_ * NMEL_ * ML_;      // 327,680
        dim3 g1(B_ * (ML_ / 64), PN_ / 64);
        convgemm_kernel<5, 1, 0, CEPI_TANHBN, 1><<<g1, 256, 0, stream>>>(
            mel, pn_w[0], pn_bv[0], pn_g, pn_bb, nullptr, pn_a, NMEL_, PN_, ML_, 0);
        dim3 gs(B_ * (ML_ / 64), PN_ / 64, 2);
        convgemm_kernel<5, 0, 0, CEPI_NONE, 2><<<gs, 256, 0, stream>>>(
            pn_a, pn_w[1], nullptr, nullptr, nullptr, nullptr, hff, PN_, PN_, ML_, psm);
        convcomb_kernel<0, CEPI_TANHBN><<<(psm + 255) / 256, 256, 0, stream>>>(
            hff, psm, pn_bv[1], pn_g + PN_, pn_bb + PN_, nullptr, pn_b2f, PN_, ML_, psm);
        convgemm_kernel<5, 0, 0, CEPI_NONE, 2><<<gs, 256, 0, stream>>>(
            pn_b2f, pn_w[2], nullptr, nullptr, nullptr, nullptr, hff, PN_, PN_, ML_, psm);
        convcomb_kernel<0, CEPI_TANHBN><<<(psm + 255) / 256, 256, 0, stream>>>(
            hff, psm, pn_bv[2], pn_g + 2 * PN_, pn_bb + 2 * PN_, nullptr, pn_a, PN_, ML_, psm);
        convgemm_kernel<5, 0, 0, CEPI_NONE, 2><<<gs, 256, 0, stream>>>(
            pn_a, pn_w[3], nullptr, nullptr, nullptr, nullptr, hff, PN_, PN_, ML_, psm);
        convcomb_kernel<0, CEPI_TANHBN><<<(psm + 255) / 256, 256, 0, stream>>>(
            hff, psm, pn_bv[3], pn_g + 3 * PN_, pn_bb + 3 * PN_, nullptr, pn_b2f, PN_, ML_, psm);
        dim3 g5(B_ * (ML_ / 64), (NMEL_ + 63) / 64, 2);
        convgemm_kernel<5, 0, 1, CEPI_NONE, 2><<<g5, 256, 0, stream>>>(
            pn_b2f, pn_w[4], nullptr, nullptr, nullptr, nullptr, hff, PN_, NMEL_, ML_, ps5);
        convcomb_kernel<1, CEPI_ADDMEL><<<(ps5 + 255) / 256, 256, 0, stream>>>(
            hff, ps5, pn_bv[4], nullptr, nullptr, mel, melp, NMEL_, ML_, ps5);
    }
}